// Round 14
// baseline (608.126 us; speedup 1.0000x reference)
//
#include <hip/hip_runtime.h>
#include <hip/hip_bf16.h>

// GIN_34789235098229 — round 23: fuse agg+mlp (LDS handoff, zero intermediate).
// Round 22 = 600.3us (MFMA mlp landed; absmax 0.125 held). Top-4 = agg @55.6us
// x4: gather at ~7.4 TB/s effective from caches (410MB logical / 55.6us) —
// structurally near its rate. The removable cost: agg->global(25.6MB)->mlp
// round-trip per layer. Fix: one fused kernel; each wave aggs its own 32 nodes
// (8 iters of the proven 4-node/wave agg), stores packed hi|lo into LDS in the
// exact format round-22 GEMM2 reads y ([row][68] uint), then GEMM1 reads
// A-fragments from LDS (same unpack as y-read), rest identical. y buffer
// aliases the handoff (row reads complete before same-row writes, in-order
// wave). Saves 51MB/layer + 4 dispatches. LDS 34816B, grid 782.

typedef unsigned short ushort_t;
typedef unsigned int uint_t;
typedef __attribute__((ext_vector_type(8))) short bf16x8;
typedef __attribute__((ext_vector_type(4))) float f32x4;

#define NN 100000
#define EE 3200000
#define GG 512
#define NBK 391    // ceil(NN/256); bucket = node >> 8
#define NHB 256    // histogram blocks
#define ECHUNK 12500  // EE / NHB exactly
#define MLPBLOCKS 782        // ceil(NN / 128 nodes-per-block)
#define NWAVE (MLPBLOCKS * 4)  // 3128 wave slots for stats partials
#define YSTRIDE 68   // LDS row stride in uints: 272B = 17x16B (aligned, low-conflict)

// ---------- detection ----------
__global__ __launch_bounds__(256) void detect_kernel(
    const uint_t* __restrict__ xw, const uint_t* __restrict__ ew,
    const uint_t* __restrict__ bw, int* __restrict__ flags)
{
    __shared__ int sb[256], se[256], sbb[256];
    int t = threadIdx.x;
    uint_t w = xw[t];
    uint_t eL = (w >> 7) & 0xffu;
    sb[t] = (eL >= 112u && eL <= 135u) ? 1 : 0;
    se[t] = (ew[2 * t + 1] == 0u) ? 1 : 0;
    sbb[t] = (bw[NN - 512 + 2 * t + 1] == 0u) ? 1 : 0;
    __syncthreads();
    for (int off = 128; off > 0; off >>= 1) {
        if (t < off) { sb[t] += sb[t + off]; se[t] += se[t + off]; sbb[t] += sbb[t + off]; }
        __syncthreads();
    }
    if (t == 0) {
        flags[0] = (sb[0] < 128) ? 1 : 0;   // 1 => fp32 floats
        flags[1] = (se[0] >= 128) ? 1 : 0;  // 1 => int64 edges
        flags[2] = (sbb[0] >= 128) ? 1 : 0; // 1 => int64 batch
    }
}

// ---------- canonicalization ----------
// wp: packed MFMA B-fragments, per layer 16384 ushorts (see round 22).
// bb: per layer 256 floats: b1[64], b2[64], gamma[64], beta[64]
__global__ __launch_bounds__(256) void cvt_w_kernel(
    const void* __restrict__ W1, const void* __restrict__ b1,
    const void* __restrict__ W2, const void* __restrict__ b2,
    const void* __restrict__ g, const void* __restrict__ be,
    const int* __restrict__ flags, ushort_t* __restrict__ wp,
    float* __restrict__ bb)
{
    int i = blockIdx.x * 256 + threadIdx.x;
    int fp32 = flags[0];
    if (i < 65536) {
        int L = i >> 14;
        int r = i & 16383;
        int gg = r >> 13;
        int p = (r >> 12) & 1;
        int t4 = (r >> 10) & 3;
        int s = (r >> 9) & 1;
        int lane = (r >> 3) & 63;
        int e = r & 7;
        int k = s * 32 + (lane >> 4) * 8 + e;
        int col = t4 * 16 + (lane & 15);
        int src = L * 4096 + k * 64 + col;
        const void* W = gg ? W2 : W1;
        float v = fp32 ? ((const float*)W)[src]
                       : __bfloat162float(((const __hip_bfloat16*)W)[src]);
        __hip_bfloat16 hb = __float2bfloat16(v);
        ushort_t outv;
        if (p) {
            __hip_bfloat16 lb = __float2bfloat16(v - __bfloat162float(hb));
            outv = *(ushort_t*)&lb;
        } else {
            outv = *(ushort_t*)&hb;
        }
        wp[i] = outv;
    } else if (i < 66560) {
        int j = i - 65536;
        int L = j >> 8;
        int r = j & 255;
        int kind = r >> 6;
        int f = r & 63;
        const void* src = (kind == 0) ? b1 : (kind == 1) ? b2 : (kind == 2) ? g : be;
        int off = L * 64 + f;
        float v = fp32 ? ((const float*)src)[off]
                       : __bfloat162float(((const __hip_bfloat16*)src)[off]);
        bb[L * 256 + kind * 64 + f] = v;
    }
}

// x -> (hi, lo) bf16 pair
__global__ __launch_bounds__(256) void cvt_x_kernel(
    const void* __restrict__ x, const int* __restrict__ flags,
    ushort_t* __restrict__ zh, ushort_t* __restrict__ zl, int total)
{
    int i = blockIdx.x * 256 + threadIdx.x;
    if (i >= total) return;
    float v;
    if (flags[0]) v = ((const float*)x)[i];
    else {
        uint_t u = (uint_t)((const ushort_t*)x)[i] << 16;
        v = __uint_as_float(u);
    }
    __hip_bfloat16 hb = __float2bfloat16(v);
    __hip_bfloat16 lb = __float2bfloat16(v - __bfloat162float(hb));
    zh[i] = *(ushort_t*)&hb;
    zl[i] = *(ushort_t*)&lb;
}

// batch is SORTED: zero-atomic group offsets via boundary detection.
__global__ __launch_bounds__(256) void cvt_batch_kernel(
    const int* __restrict__ bw, const int* __restrict__ flags,
    int* __restrict__ b32, int* __restrict__ gstart, int n)
{
    int i = blockIdx.x * 256 + threadIdx.x;
    if (i >= n) return;
    int i64 = flags[2];
    int v = i64 ? bw[2 * i] : bw[i];
    b32[i] = v;
    int vn = (i + 1 < n) ? (i64 ? bw[2 * (i + 1)] : bw[i + 1]) : GG;
    if (i == 0) {
        for (int g = 0; g <= v; ++g) gstart[g] = 0;
    }
    if (vn != v) {
        for (int g = v + 1; g <= vn; ++g) gstart[g] = i + 1;
    }
}

// ---------- atomic-free CSR build (unchanged) ----------
__global__ __launch_bounds__(256) void count_hist_kernel(
    const int* __restrict__ ei, const int* __restrict__ flags,
    int* __restrict__ histo, int E)
{
    __shared__ int lh[NBK];
    int b = blockIdx.x, t = threadIdx.x;
    for (int j = t; j < NBK; j += 256) lh[j] = 0;
    __syncthreads();
    int i64 = flags[1];
    int e0 = b * ECHUNK, e1 = min(e0 + ECHUNK, E);
    for (int i = e0 + t; i < e1; i += 256) {
        int d = i64 ? ei[2 * (E + i)] : ei[E + i];
        atomicAdd(&lh[d >> 8], 1);
    }
    __syncthreads();
    for (int j = t; j < NBK; j += 256) histo[j * NHB + b] = lh[j];
}

__global__ __launch_bounds__(NHB) void blockscan_kernel(
    int* __restrict__ histo, int* __restrict__ tot)
{
    __shared__ int sd[NHB];
    int j = blockIdx.x, t = threadIdx.x;
    int v = histo[j * NHB + t];
    sd[t] = v;
    __syncthreads();
    #pragma unroll
    for (int off = 1; off < NHB; off <<= 1) {
        int add = (t >= off) ? sd[t - off] : 0;
        __syncthreads();
        sd[t] += add;
        __syncthreads();
    }
    histo[j * NHB + t] = sd[t] - v;
    if (t == NHB - 1) tot[j] = sd[NHB - 1];
}

__global__ __launch_bounds__(512) void bscan_kernel(
    const int* __restrict__ tot, int* __restrict__ bktoff)
{
    __shared__ int sd[512];
    int t = threadIdx.x;
    int v = (t < NBK) ? tot[t] : 0;
    sd[t] = v;
    __syncthreads();
    #pragma unroll
    for (int off = 1; off < 512; off <<= 1) {
        int add = (t >= off) ? sd[t - off] : 0;
        __syncthreads();
        sd[t] += add;
        __syncthreads();
    }
    if (t < NBK) bktoff[t] = sd[t] - v;
    if (t == 511) bktoff[NBK] = sd[511];
}

__global__ __launch_bounds__(256) void pair_scatter_kernel(
    const int* __restrict__ ei, const int* __restrict__ flags,
    const int* __restrict__ histo, const int* __restrict__ bktoff,
    int2* __restrict__ pairs, int E)
{
    __shared__ int cur[NBK];
    int b = blockIdx.x, t = threadIdx.x;
    for (int j = t; j < NBK; j += 256) cur[j] = histo[j * NHB + b] + bktoff[j];
    __syncthreads();
    int i64 = flags[1];
    int e0 = b * ECHUNK, e1 = min(e0 + ECHUNK, E);
    for (int i = e0 + t; i < e1; i += 256) {
        int d = i64 ? ei[2 * (E + i)] : ei[E + i];
        int s = i64 ? ei[2 * i]       : ei[i];
        int p = atomicAdd(&cur[d >> 8], 1);
        pairs[p] = make_int2(d, s);
    }
}

__global__ __launch_bounds__(256) void bucket_deg_kernel(
    const int2* __restrict__ pairs, const int* __restrict__ bktoff,
    int* __restrict__ deg, int N)
{
    __shared__ int cnt[256];
    int j = blockIdx.x, t = threadIdx.x;
    cnt[t] = 0;
    __syncthreads();
    int e0 = bktoff[j], e1 = bktoff[j + 1];
    for (int i = e0 + t; i < e1; i += 256)
        atomicAdd(&cnt[pairs[i].x & 255], 1);
    __syncthreads();
    int idx = j * 256 + t;
    if (idx < N) deg[idx] = cnt[t];
}

__global__ __launch_bounds__(256) void scan1_kernel(
    const int* __restrict__ deg, int* __restrict__ part, int* __restrict__ bsum, int n)
{
    __shared__ int sd[256];
    int t = threadIdx.x;
    int i0 = blockIdx.x * 1024 + t * 4;
    int v0 = 0, v1 = 0, v2 = 0, v3 = 0;
    if (i0 + 3 < n) {
        int4 v = *(const int4*)(deg + i0);
        v0 = v.x; v1 = v.y; v2 = v.z; v3 = v.w;
    } else if (i0 < n) {
        v0 = deg[i0];
        if (i0 + 1 < n) v1 = deg[i0 + 1];
        if (i0 + 2 < n) v2 = deg[i0 + 2];
    }
    int s = v0 + v1 + v2 + v3;
    sd[t] = s;
    __syncthreads();
    #pragma unroll
    for (int off = 1; off < 256; off <<= 1) {
        int add = (t >= off) ? sd[t - off] : 0;
        __syncthreads();
        sd[t] += add;
        __syncthreads();
    }
    int incl = sd[t];
    int e0 = incl - s;
    int p0 = e0 + v0, p1 = p0 + v1, p2 = p1 + v2, p3 = p2 + v3;
    if (i0 < n)     part[i0]     = p0;
    if (i0 + 1 < n) part[i0 + 1] = p1;
    if (i0 + 2 < n) part[i0 + 2] = p2;
    if (i0 + 3 < n) part[i0 + 3] = p3;
    if (t == 255) bsum[blockIdx.x] = incl;
}

__global__ __launch_bounds__(128) void scan2_kernel(int* __restrict__ bsum, int nb)
{
    __shared__ int sd[128];
    int t = threadIdx.x;
    int own = (t < nb) ? bsum[t] : 0;
    sd[t] = own;
    __syncthreads();
    #pragma unroll
    for (int off = 1; off < 128; off <<= 1) {
        int add = (t >= off) ? sd[t - off] : 0;
        __syncthreads();
        sd[t] += add;
        __syncthreads();
    }
    if (t < nb) bsum[t] = sd[t] - own;
}

__global__ __launch_bounds__(256) void scan3_kernel(
    const int* __restrict__ part, const int* __restrict__ bsum,
    const int* __restrict__ deg, int* __restrict__ indptr,
    float* __restrict__ inv_deg, int n)
{
    int i = blockIdx.x * 256 + threadIdx.x;
    if (i >= n) return;
    int val = part[i] + bsum[i >> 10];
    indptr[i + 1] = val;
    int d = deg[i];
    inv_deg[i] = (d > 0) ? 1.0f / (float)d : 0.0f;
    if (i == 0) indptr[0] = 0;
}

// invg from sorted-boundary gstart + identity-init of ac slot 0 (A=1, C=0)
__global__ __launch_bounds__(512) void invg_kernel(
    const int* __restrict__ gstart, float* __restrict__ invg,
    float* __restrict__ ac, int G)
{
    int g = threadIdx.x;
    if (g < G) {
        int c = gstart[g + 1] - gstart[g];
        invg[g] = (c > 0) ? 1.0f / (float)c : 0.0f;
    }
    if (g < 64) ac[g] = 1.0f;
    else if (g < 128) ac[g] = 0.0f;
}

__global__ __launch_bounds__(256) void csr_fill_kernel(
    const int2* __restrict__ pairs, const int* __restrict__ bktoff,
    const int* __restrict__ indptr, int* __restrict__ esrc, int N)
{
    __shared__ int cur[256];
    int j = blockIdx.x, t = threadIdx.x;
    int idx = j * 256 + t;
    cur[t] = (idx < N) ? indptr[idx] : 0;
    __syncthreads();
    int e0 = bktoff[j], e1 = bktoff[j + 1];
    for (int i = e0 + t; i < e1; i += 256) {
        int2 e = pairs[i];
        int p = atomicAdd(&cur[e.x & 255], 1);
        esrc[p] = e.y;
    }
}

// ---------- per-layer: fused agg + MFMA mlp ----------
// Phase A (agg): per wave, 8 iterations x 4 nodes (16-lane groups, edge-index
// broadcast, 16-deep gather batches). Result packed hi|lo -> LDS [row][68].
// Phase B (mlp): round-22 MFMA GEMM1/GEMM2; A-fragments unpacked from LDS
// (same format as y). y aliases the handoff rows (read-before-overwrite,
// in-order wave). Stats butterfly + coalesced (zh,zl) stores unchanged.
__global__ __launch_bounds__(256) void fused_kernel(
    const ushort_t* __restrict__ zh_in, const ushort_t* __restrict__ zl_in,
    const int* __restrict__ indptr, const int* __restrict__ esrc,
    const float* __restrict__ inv_deg, const float* __restrict__ ac,
    const ushort_t* __restrict__ wp, const float* __restrict__ bb,
    ushort_t* __restrict__ zh_out, ushort_t* __restrict__ zl_out,
    float* __restrict__ partials, int n)
{
    __shared__ uint_t ylds[4 * 32 * YSTRIDE];
    int tid = threadIdx.x;
    int lane = tid & 63;
    int w = tid >> 6;
    int nb = blockIdx.x * 128 + w * 32;
    int wid = blockIdx.x * 4 + w;
    uint_t* my = ylds + w * 32 * YSTRIDE;

    // ---- Phase A: agg 32 nodes into LDS ----
    {
        int grpw = lane >> 4;        // group 0..3 within wave
        int l = lane & 15;
        int gl0 = lane & 48;         // group base lane
        const ushort_t* zbl = zh_in + l * 4;
        #pragma unroll 1
        for (int it = 0; it < 8; ++it) {
            int nl = it * 4 + grpw;          // local row 0..31
            int node = nb + nl;
            float4 r = make_float4(0.f, 0.f, 0.f, 0.f);
            if (node < n) {
                int e0 = indptr[node], e1 = indptr[node + 1];
                float idg = inv_deg[node];
                uint2 uh = *(const uint2*)(zh_in + (size_t)node * 64 + l * 4);
                uint2 ul = *(const uint2*)(zl_in + (size_t)node * 64 + l * 4);
                float4 own;
                own.x = __uint_as_float(uh.x << 16) + __uint_as_float(ul.x << 16);
                own.y = __uint_as_float(uh.x & 0xffff0000u) + __uint_as_float(ul.x & 0xffff0000u);
                own.z = __uint_as_float(uh.y << 16) + __uint_as_float(ul.y << 16);
                own.w = __uint_as_float(uh.y & 0xffff0000u) + __uint_as_float(ul.y & 0xffff0000u);
                float4 A = *(const float4*)(ac + l * 4);
                float4 C = *(const float4*)(ac + 64 + l * 4);
                float a0 = 0.f, a1 = 0.f, a2 = 0.f, a3 = 0.f;
                int base = e0;
                for (; base + 16 <= e1; base += 16) {
                    int myi = esrc[base + l];
                    uint2 vv[16];
                    #pragma unroll
                    for (int j = 0; j < 16; ++j) {
                        int s = __shfl(myi, gl0 + j, 64);
                        vv[j] = *(const uint2*)(zbl + (size_t)s * 64);
                    }
                    #pragma unroll
                    for (int j = 0; j < 16; ++j) {
                        a0 += __uint_as_float(vv[j].x << 16);
                        a1 += __uint_as_float(vv[j].x & 0xffff0000u);
                        a2 += __uint_as_float(vv[j].y << 16);
                        a3 += __uint_as_float(vv[j].y & 0xffff0000u);
                    }
                }
                int cnt = e1 - base;
                if (cnt > 0) {
                    int myi = (l < cnt) ? esrc[base + l] : 0;
                    uint2 vv[16];
                    #pragma unroll
                    for (int j = 0; j < 16; ++j) {
                        int jj = (j < cnt) ? j : 0;
                        int s = __shfl(myi, gl0 + jj, 64);
                        uint2 v = *(const uint2*)(zbl + (size_t)s * 64);
                        vv[j].x = (j < cnt) ? v.x : 0u;
                        vv[j].y = (j < cnt) ? v.y : 0u;
                    }
                    #pragma unroll
                    for (int j = 0; j < 16; ++j) {
                        a0 += __uint_as_float(vv[j].x << 16);
                        a1 += __uint_as_float(vv[j].x & 0xffff0000u);
                        a2 += __uint_as_float(vv[j].y << 16);
                        a3 += __uint_as_float(vv[j].y & 0xffff0000u);
                    }
                }
                float cf = (idg > 0.f) ? 2.f : 1.f;
                r.x = fmaf(A.x, fmaf(idg, a0, own.x), C.x * cf);
                r.y = fmaf(A.y, fmaf(idg, a1, own.y), C.y * cf);
                r.z = fmaf(A.z, fmaf(idg, a2, own.z), C.z * cf);
                r.w = fmaf(A.w, fmaf(idg, a3, own.w), C.w * cf);
            }
            // pack hi|lo per feature and store 16B to LDS
            __hip_bfloat16 hx = __float2bfloat16(r.x);
            __hip_bfloat16 hy = __float2bfloat16(r.y);
            __hip_bfloat16 hz = __float2bfloat16(r.z);
            __hip_bfloat16 hw = __float2bfloat16(r.w);
            __hip_bfloat16 lx = __float2bfloat16(r.x - __bfloat162float(hx));
            __hip_bfloat16 ly = __float2bfloat16(r.y - __bfloat162float(hy));
            __hip_bfloat16 lz = __float2bfloat16(r.z - __bfloat162float(hz));
            __hip_bfloat16 lw = __float2bfloat16(r.w - __bfloat162float(hw));
            uint4 u;
            u.x = (uint_t)*(ushort_t*)&hx | ((uint_t)*(ushort_t*)&lx << 16);
            u.y = (uint_t)*(ushort_t*)&hy | ((uint_t)*(ushort_t*)&ly << 16);
            u.z = (uint_t)*(ushort_t*)&hz | ((uint_t)*(ushort_t*)&lz << 16);
            u.w = (uint_t)*(ushort_t*)&hw | ((uint_t)*(ushort_t*)&lw << 16);
            *(uint4*)(my + nl * YSTRIDE + l * 4) = u;
        }
    }
    // wave-private LDS: no barrier needed (in-order LDS ops within wave)

    int c = lane & 15, q = lane >> 4;

    // ---- GEMM1 (A from LDS handoff) ----
    #pragma unroll
    for (int mt = 0; mt < 2; ++mt) {
        int nl = mt * 16 + c;
        bf16x8 aah[2], aal[2];
        #pragma unroll
        for (int s = 0; s < 2; ++s) {
            const uint_t* pa = my + nl * YSTRIDE + s * 32 + q * 8;
            uint4 ua = *(const uint4*)(pa);
            uint4 ub = *(const uint4*)(pa + 4);
            aah[s][0] = (short)(ua.x & 0xffffu); aal[s][0] = (short)(ua.x >> 16);
            aah[s][1] = (short)(ua.y & 0xffffu); aal[s][1] = (short)(ua.y >> 16);
            aah[s][2] = (short)(ua.z & 0xffffu); aal[s][2] = (short)(ua.z >> 16);
            aah[s][3] = (short)(ua.w & 0xffffu); aal[s][3] = (short)(ua.w >> 16);
            aah[s][4] = (short)(ub.x & 0xffffu); aal[s][4] = (short)(ub.x >> 16);
            aah[s][5] = (short)(ub.y & 0xffffu); aal[s][5] = (short)(ub.y >> 16);
            aah[s][6] = (short)(ub.z & 0xffffu); aal[s][6] = (short)(ub.z >> 16);
            aah[s][7] = (short)(ub.w & 0xffffu); aal[s][7] = (short)(ub.w >> 16);
        }
        f32x4 acc[4] = {{0.f,0.f,0.f,0.f},{0.f,0.f,0.f,0.f},{0.f,0.f,0.f,0.f},{0.f,0.f,0.f,0.f}};
        #pragma unroll
        for (int t4 = 0; t4 < 4; ++t4) {
            #pragma unroll
            for (int s = 0; s < 2; ++s) {
                bf16x8 bh = *(const bf16x8*)(wp + (size_t)((t4 * 2 + s) * 512) + lane * 8);
                bf16x8 bl = *(const bf16x8*)(wp + (size_t)((8 + t4 * 2 + s) * 512) + lane * 8);
                acc[t4] = __builtin_amdgcn_mfma_f32_16x16x32_bf16(aal[s], bh, acc[t4], 0, 0, 0);
                acc[t4] = __builtin_amdgcn_mfma_f32_16x16x32_bf16(aah[s], bl, acc[t4], 0, 0, 0);
                acc[t4] = __builtin_amdgcn_mfma_f32_16x16x32_bf16(aah[s], bh, acc[t4], 0, 0, 0);
            }
        }
        #pragma unroll
        for (int t4 = 0; t4 < 4; ++t4) {
            float b = bb[t4 * 16 + c];
            #pragma unroll
            for (int r = 0; r < 4; ++r) {
                float y = fmaxf(acc[t4][r] + b, 0.f);
                __hip_bfloat16 hb = __float2bfloat16(y);
                __hip_bfloat16 lb = __float2bfloat16(y - __bfloat162float(hb));
                uint_t u = (uint_t)*(ushort_t*)&hb | ((uint_t)*(ushort_t*)&lb << 16);
                my[(mt * 16 + q * 4 + r) * YSTRIDE + t4 * 16 + c] = u;
            }
        }
    }
    __syncthreads();

    // ---- GEMM2 ----
    float ssum[4] = {0.f, 0.f, 0.f, 0.f};
    float ssq[4] = {0.f, 0.f, 0.f, 0.f};
    #pragma unroll
    for (int mt = 0; mt < 2; ++mt) {
        int nl = mt * 16 + c;
        bf16x8 yah[2], yal[2];
        #pragma unroll
        for (int s = 0; s < 2; ++s) {
            const uint_t* pa = my + nl * YSTRIDE + s * 32 + q * 8;
            uint4 ua = *(const uint4*)(pa);
            uint4 ub = *(const uint4*)(pa + 4);
            yah[s][0] = (short)(ua.x & 0xffffu); yal[s][0] = (short)(ua.x >> 16);
            yah[s][1] = (short)(ua.y & 0xffffu); yal[s][1] = (short)(ua.y >> 16);
            yah[s][2] = (short)(ua.z & 0xffffu); yal[s][2] = (short)(ua.z >> 16);
            yah[s][3] = (short)(ua.w & 0xffffu); yal[s][3] = (short)(ua.w >> 16);
            yah[s][4] = (short)(ub.x & 0xffffu); yal[s][4] = (short)(ub.x >> 16);
            yah[s][5] = (short)(ub.y & 0xffffu); yal[s][5] = (short)(ub.y >> 16);
            yah[s][6] = (short)(ub.z & 0xffffu); yal[s][6] = (short)(ub.z >> 16);
            yah[s][7] = (short)(ub.w & 0xffffu); yal[s][7] = (short)(ub.w >> 16);
        }
        f32x4 acc[4] = {{0.f,0.f,0.f,0.f},{0.f,0.f,0.f,0.f},{0.f,0.f,0.f,0.f},{0.f,0.f,0.f,0.f}};
        #pragma unroll
        for (int t4 = 0; t4 < 4; ++t4) {
            #pragma unroll
            for (int s = 0; s < 2; ++s) {
                bf16x8 bh = *(const bf16x8*)(wp + (size_t)((16 + t4 * 2 + s) * 512) + lane * 8);
                bf16x8 bl = *(const bf16x8*)(wp + (size_t)((24 + t4 * 2 + s) * 512) + lane * 8);
                acc[t4] = __builtin_amdgcn_mfma_f32_16x16x32_bf16(yal[s], bh, acc[t4], 0, 0, 0);
                acc[t4] = __builtin_amdgcn_mfma_f32_16x16x32_bf16(yah[s], bl, acc[t4], 0, 0, 0);
                acc[t4] = __builtin_amdgcn_mfma_f32_16x16x32_bf16(yah[s], bh, acc[t4], 0, 0, 0);
            }
        }
        #pragma unroll
        for (int t4 = 0; t4 < 4; ++t4) {
            float b = bb[64 + t4 * 16 + c];
            #pragma unroll
            for (int r = 0; r < 4; ++r) {
                int node = nb + mt * 16 + q * 4 + r;
                float h = fmaxf(acc[t4][r] + b, 0.f);
                float hv = (node < n) ? h : 0.f;
                ssum[t4] += hv;
                ssq[t4] += hv * hv;
                my[(mt * 16 + q * 4 + r) * YSTRIDE + t4 * 16 + c] = __float_as_uint(h);
            }
        }
    }
    __syncthreads();

    // stats butterfly across the 4 quadrants (rows); lanes 0..15 store
    #pragma unroll
    for (int t4 = 0; t4 < 4; ++t4) {
        ssum[t4] += __shfl_xor(ssum[t4], 16, 64);
        ssum[t4] += __shfl_xor(ssum[t4], 32, 64);
        ssq[t4]  += __shfl_xor(ssq[t4], 16, 64);
        ssq[t4]  += __shfl_xor(ssq[t4], 32, 64);
    }
    if (lane < 16) {
        #pragma unroll
        for (int t4 = 0; t4 < 4; ++t4) {
            partials[(size_t)(t4 * 16 + lane) * NWAVE + wid] = ssum[t4];
            partials[(size_t)(64 + t4 * 16 + lane) * NWAVE + wid] = ssq[t4];
        }
    }

    // store phase: coalesced (zh, zl) from LDS h
    #pragma unroll
    for (int cc = 0; cc < 8; ++cc) {
        int li = lane + 64 * cc;
        int nl = li >> 4, fg = li & 15;
        int node = nb + nl;
        if (node < n) {
            uint4 u = *(const uint4*)(my + nl * YSTRIDE + fg * 4);
            float f0 = __uint_as_float(u.x);
            float f1 = __uint_as_float(u.y);
            float f2 = __uint_as_float(u.z);
            float f3 = __uint_as_float(u.w);
            __hip_bfloat16 h0 = __float2bfloat16(f0);
            __hip_bfloat16 h1 = __float2bfloat16(f1);
            __hip_bfloat16 h2 = __float2bfloat16(f2);
            __hip_bfloat16 h3 = __float2bfloat16(f3);
            __hip_bfloat16 l0 = __float2bfloat16(f0 - __bfloat162float(h0));
            __hip_bfloat16 l1 = __float2bfloat16(f1 - __bfloat162float(h1));
            __hip_bfloat16 l2 = __float2bfloat16(f2 - __bfloat162float(h2));
            __hip_bfloat16 l3 = __float2bfloat16(f3 - __bfloat162float(h3));
            uint2 ph, pl;
            ph.x = (uint_t)*(ushort_t*)&h0 | ((uint_t)*(ushort_t*)&h1 << 16);
            ph.y = (uint_t)*(ushort_t*)&h2 | ((uint_t)*(ushort_t*)&h3 << 16);
            pl.x = (uint_t)*(ushort_t*)&l0 | ((uint_t)*(ushort_t*)&l1 << 16);
            pl.y = (uint_t)*(ushort_t*)&l2 | ((uint_t)*(ushort_t*)&l3 << 16);
            *(uint2*)(zh_out + (size_t)node * 64 + fg * 4) = ph;
            *(uint2*)(zl_out + (size_t)node * 64 + fg * 4) = pl;
        }
    }
}

// reduce per-wave partials -> BN affine (A,C) for this layer's ac slot.
__global__ __launch_bounds__(256) void redstats_kernel(
    const float* __restrict__ partials, const float* __restrict__ gammaf,
    const float* __restrict__ betaf, float* __restrict__ ac_out)
{
    __shared__ float s1[256], s2[256];
    int f = blockIdx.x;
    int t = threadIdx.x;
    const float* ph = partials + (size_t)f * NWAVE;
    const float* pq = partials + (size_t)(64 + f) * NWAVE;
    float a = 0.f, b = 0.f;
    for (int i = t; i < NWAVE; i += 256) { a += ph[i]; b += pq[i]; }
    s1[t] = a; s2[t] = b;
    __syncthreads();
    for (int off = 128; off > 0; off >>= 1) {
        if (t < off) { s1[t] += s1[t + off]; s2[t] += s2[t + off]; }
        __syncthreads();
    }
    if (t == 0) {
        const float invN = 1.0f / (float)NN;
        float mu = s1[0] * invN;
        float var = s2[0] * invN - mu * mu;
        if (var < 0.f) var = 0.f;
        float A = gammaf[f] * rsqrtf(var + 1e-5f);
        float C = betaf[f] - mu * A;
        ac_out[f] = A;
        ac_out[64 + f] = C;
    }
}

// pools: z = hi+lo; h = A*z + C; node_pool (+=) or (l==3) direct write to out;
// gpool run-length atomics.
__global__ __launch_bounds__(256) void pool_kernel(
    const ushort_t* __restrict__ zh, const ushort_t* __restrict__ zl,
    float* __restrict__ node_pool, const int* __restrict__ b32,
    const float* __restrict__ ac, float* __restrict__ gpool,
    const int* __restrict__ flags, void* __restrict__ out,
    int N, int first, int last)
{
    int wave = (blockIdx.x * 256 + threadIdx.x) >> 6;
    int f = threadIdx.x & 63;
    int n0 = wave * 16;
    if (n0 >= N) return;
    int n1 = min(n0 + 16, N);
    float A = ac[f], C = ac[64 + f];
    int fp32 = flags[0];
    float racc = 0.f;
    int cur = b32[n0];
    int n = n0;
    for (; n + 4 <= n1; n += 4) {
        int4 gv = *(const int4*)(b32 + n);
        size_t idx = (size_t)n * 64 + f;
        float z0 = __uint_as_float((uint_t)zh[idx] << 16)       + __uint_as_float((uint_t)zl[idx] << 16);
        float z1 = __uint_as_float((uint_t)zh[idx + 64] << 16)  + __uint_as_float((uint_t)zl[idx + 64] << 16);
        float z2 = __uint_as_float((uint_t)zh[idx + 128] << 16) + __uint_as_float((uint_t)zl[idx + 128] << 16);
        float z3 = __uint_as_float((uint_t)zh[idx + 192] << 16) + __uint_as_float((uint_t)zl[idx + 192] << 16);
        float h0 = fmaf(z0, A, C);
        float h1 = fmaf(z1, A, C);
        float h2 = fmaf(z2, A, C);
        float h3 = fmaf(z3, A, C);
        float p0, p1, p2, p3;
        if (first) {
            p0 = h0; p1 = h1; p2 = h2; p3 = h3;
        } else {
            p0 = node_pool[idx]       + h0;
            p1 = node_pool[idx + 64]  + h1;
            p2 = node_pool[idx + 128] + h2;
            p3 = node_pool[idx + 192] + h3;
        }
        if (last) {
            if (fp32) {
                ((float*)out)[idx]       = p0;
                ((float*)out)[idx + 64]  = p1;
                ((float*)out)[idx + 128] = p2;
                ((float*)out)[idx + 192] = p3;
            } else {
                __hip_bfloat16 b0 = __float2bfloat16(p0);
                __hip_bfloat16 b1 = __float2bfloat16(p1);
                __hip_bfloat16 b2 = __float2bfloat16(p2);
                __hip_bfloat16 b3 = __float2bfloat16(p3);
                ((__hip_bfloat16*)out)[idx]       = b0;
                ((__hip_bfloat16*)out)[idx + 64]  = b1;
                ((__hip_bfloat16*)out)[idx + 128] = b2;
                ((__hip_bfloat16*)out)[idx + 192] = b3;
            }
        } else {
            node_pool[idx]       = p0;
            node_pool[idx + 64]  = p1;
            node_pool[idx + 128] = p2;
            node_pool[idx + 192] = p3;
        }
        int gs0 = gv.x, gs1 = gv.y, gs2 = gv.z, gs3 = gv.w;
        if (gs0 != cur) { atomicAdd(&gpool[(size_t)cur * 64 + f], racc); racc = 0.f; cur = gs0; }
        racc += h0;
        if (gs1 != cur) { atomicAdd(&gpool[(size_t)cur * 64 + f], racc); racc = 0.f; cur = gs1; }
        racc += h1;
        if (gs2 != cur) { atomicAdd(&gpool[(size_t)cur * 64 + f], racc); racc = 0.f; cur = gs2; }
        racc += h2;
        if (gs3 != cur) { atomicAdd(&gpool[(size_t)cur * 64 + f], racc); racc = 0.f; cur = gs3; }
        racc += h3;
    }
    for (; n < n1; ++n) {  // tail (unused when 16 | N; kept for safety)
        int g = b32[n];
        if (g != cur) { atomicAdd(&gpool[(size_t)cur * 64 + f], racc); racc = 0.f; cur = g; }
        size_t idx = (size_t)n * 64 + f;
        float zv = __uint_as_float((uint_t)zh[idx] << 16) + __uint_as_float((uint_t)zl[idx] << 16);
        float hv = fmaf(zv, A, C);
        float np = first ? hv : (node_pool[idx] + hv);
        if (last) {
            if (fp32) ((float*)out)[idx] = np;
            else ((__hip_bfloat16*)out)[idx] = __float2bfloat16(np);
        } else node_pool[idx] = np;
        racc += hv;
    }
    atomicAdd(&gpool[(size_t)cur * 64 + f], racc);
}

// finalize: gpool tail only (node section written by pool l==3)
__global__ __launch_bounds__(256) void finalize_kernel(
    const float* __restrict__ gpool, const float* __restrict__ invg,
    const int* __restrict__ flags, void* __restrict__ out, int N)
{
    int i = blockIdx.x * 256 + threadIdx.x;
    if (i >= GG * 64) return;
    float v = gpool[i] * invg[i >> 6];
    int nd = N * 64;
    if (flags[0]) ((float*)out)[nd + i] = v;
    else ((__hip_bfloat16*)out)[nd + i] = __float2bfloat16(v);
}

extern "C" void kernel_launch(void* const* d_in, const int* in_sizes, int n_in,
                              void* d_out, int out_size, void* d_ws, size_t ws_size,
                              hipStream_t stream)
{
    constexpr int N = NN, E = EE, G = GG;
    constexpr int ND = N * 64;

    const void* x     = d_in[0];
    const void* W1    = d_in[1];
    const void* b1    = d_in[2];
    const void* W2    = d_in[3];
    const void* b2    = d_in[4];
    const void* gamma = d_in[5];
    const void* beta  = d_in[6];
    const int* ei     = (const int*)d_in[7];
    const int* batw   = (const int*)d_in[8];

    char* p = (char*)d_ws;
    auto alloc = [&](size_t bytes) -> char* {
        char* r = p;
        p += (bytes + 255) & ~(size_t)255;
        return r;
    };
    ushort_t* zhA      = (ushort_t*)alloc((size_t)ND * 2);
    ushort_t* zlA      = (ushort_t*)alloc((size_t)ND * 2);
    ushort_t* zhB      = (ushort_t*)alloc((size_t)ND * 2);
    ushort_t* zlB      = (ushort_t*)alloc((size_t)ND * 2);
    float*    node_pool = (float*)alloc((size_t)ND * 4);
    int*      esrc      = (int*)alloc((size_t)E * 4);
    int*      indptr    = (int*)alloc((size_t)(N + 1) * 4);
    int*      deg       = (int*)alloc((size_t)N * 4);
    int*      part      = (int*)alloc((size_t)N * 4);
    float*    invdeg    = (float*)alloc((size_t)N * 4);
    int*      b32       = (int*)alloc((size_t)N * 4);
    int*      bsum      = (int*)alloc(128 * 4);
    int*      gstart    = (int*)alloc((size_t)(G + 1) * 4);
    float*    invg      = (float*)alloc(G * 4);
    float*    gpool     = (float*)alloc((size_t)G * 64 * 4);
    float*    ac5       = (float*)alloc(5 * 128 * 4);  // slot0 identity, slots1..4 BN_l
    float*    partials  = (float*)alloc((size_t)128 * NWAVE * 4);  // 1.6 MB
    ushort_t* wp        = (ushort_t*)alloc((size_t)4 * 16384 * 2); // packed weights
    float*    bb        = (float*)alloc(4 * 256 * 4);  // b1,b2,gamma,beta per layer
    int*      flags     = (int*)alloc(16 * 4);
    int*      histo     = (int*)alloc((size_t)NBK * NHB * 4);
    int*      tot       = (int*)alloc((size_t)NBK * 4);
    int*      bktoff    = (int*)alloc((size_t)(NBK + 1) * 4);
    // pairs aliases node_pool: dead until first pool_kernel; E*8 == ND*4 bytes
    int2*     pairs     = (int2*)node_pool;

    hipMemsetAsync(gpool, 0, (size_t)G * 64 * 4, stream);

    detect_kernel<<<1, 256, 0, stream>>>(
        (const uint_t*)x, (const uint_t*)ei, (const uint_t*)batw, flags);
    cvt_w_kernel<<<260, 256, 0, stream>>>(W1, b1, W2, b2, gamma, beta, flags, wp, bb);
    cvt_x_kernel<<<(ND + 255) / 256, 256, 0, stream>>>(x, flags, zhA, zlA, ND);
    cvt_batch_kernel<<<(N + 255) / 256, 256, 0, stream>>>(batw, flags, b32, gstart, N);
    count_hist_kernel<<<NHB, 256, 0, stream>>>(ei, flags, histo, E);
    blockscan_kernel<<<NBK, NHB, 0, stream>>>(histo, tot);
    bscan_kernel<<<1, 512, 0, stream>>>(tot, bktoff);
    pair_scatter_kernel<<<NHB, 256, 0, stream>>>(ei, flags, histo, bktoff, pairs, E);
    bucket_deg_kernel<<<NBK, 256, 0, stream>>>(pairs, bktoff, deg, N);
    int nb = (N + 1023) / 1024;  // 98
    scan1_kernel<<<nb, 256, 0, stream>>>(deg, part, bsum, N);
    scan2_kernel<<<1, 128, 0, stream>>>(bsum, nb);
    scan3_kernel<<<(N + 255) / 256, 256, 0, stream>>>(part, bsum, deg, indptr, invdeg, N);
    invg_kernel<<<1, 512, 0, stream>>>(gstart, invg, ac5, G);
    csr_fill_kernel<<<NBK, 256, 0, stream>>>(pairs, bktoff, indptr, esrc, N);

    ushort_t* zh_in = zhA; ushort_t* zl_in = zlA;
    ushort_t* zh_out = zhB; ushort_t* zl_out = zlB;
    for (int l = 0; l < 4; ++l) {
        fused_kernel<<<MLPBLOCKS, 256, 0, stream>>>(
            zh_in, zl_in, indptr, esrc, invdeg, ac5 + l * 128,
            wp + (size_t)l * 16384, bb + l * 256,
            zh_out, zl_out, partials, N);
        redstats_kernel<<<64, 256, 0, stream>>>(
            partials, bb + l * 256 + 128, bb + l * 256 + 192,
            ac5 + (l + 1) * 128);
        pool_kernel<<<(N + 63) / 64, 256, 0, stream>>>(
            zh_out, zl_out, node_pool, b32, ac5 + (l + 1) * 128, gpool, flags, d_out,
            N, (l == 0) ? 1 : 0, (l == 3) ? 1 : 0);
        ushort_t* th = zh_in; zh_in = zh_out; zh_out = th;
        ushort_t* tl = zl_in; zl_in = zl_out; zl_out = tl;
    }
    finalize_kernel<<<128, 256, 0, stream>>>(gpool, invg, flags, d_out, N);
}

// Round 15
// 579.302 us; speedup vs baseline: 1.0498x; 1.0498x over previous
//
#include <hip/hip_runtime.h>
#include <hip/hip_bf16.h>

// GIN_34789235098229 — round 24: revert fusion (round-22 structure) + gpool
// linearity + pool->agg fold.
// Round 23 = 608us (fusion FAILED: gather is concurrency-limited — fused 3128
// waves vs 25000 agg waves dropped fetch BW 3.5->2.5 TB/s; reverted).
// New: (1) gpool = segsum(node_pool_final)*invg (linear across layers) => only
// the last pool needs gpool (run-length over final p). (2) pool_l folded into
// agg_{l+1}: h = A*own+C (4 FMAs, same ac slot agg loads) + float4 node_pool
// rmw issued before the gather loop (hidden under gather latency). Pools 0-2
// deleted; one standalone pool after layer 3 writes out + gpool. mlp = round-22
// MFMA split-bf16 exact.

typedef unsigned short ushort_t;
typedef unsigned int uint_t;
typedef __attribute__((ext_vector_type(8))) short bf16x8;
typedef __attribute__((ext_vector_type(4))) float f32x4;

#define NN 100000
#define EE 3200000
#define GG 512
#define NBK 391    // ceil(NN/256); bucket = node >> 8
#define NHB 256    // histogram blocks
#define ECHUNK 12500  // EE / NHB exactly
#define MLPBLOCKS 782        // ceil(NN / 128 nodes-per-block)
#define NWAVE (MLPBLOCKS * 4)  // 3128 wave slots for stats partials
#define YSTRIDE 68   // LDS row stride in uints: 272B = 17x16B (aligned, low-conflict)

// ---------- detection ----------
__global__ __launch_bounds__(256) void detect_kernel(
    const uint_t* __restrict__ xw, const uint_t* __restrict__ ew,
    const uint_t* __restrict__ bw, int* __restrict__ flags)
{
    __shared__ int sb[256], se[256], sbb[256];
    int t = threadIdx.x;
    uint_t w = xw[t];
    uint_t eL = (w >> 7) & 0xffu;
    sb[t] = (eL >= 112u && eL <= 135u) ? 1 : 0;
    se[t] = (ew[2 * t + 1] == 0u) ? 1 : 0;
    sbb[t] = (bw[NN - 512 + 2 * t + 1] == 0u) ? 1 : 0;
    __syncthreads();
    for (int off = 128; off > 0; off >>= 1) {
        if (t < off) { sb[t] += sb[t + off]; se[t] += se[t + off]; sbb[t] += sbb[t + off]; }
        __syncthreads();
    }
    if (t == 0) {
        flags[0] = (sb[0] < 128) ? 1 : 0;   // 1 => fp32 floats
        flags[1] = (se[0] >= 128) ? 1 : 0;  // 1 => int64 edges
        flags[2] = (sbb[0] >= 128) ? 1 : 0; // 1 => int64 batch
    }
}

// ---------- canonicalization ----------
// wp: packed MFMA B-fragments, per layer 16384 ushorts (see round 22).
// bb: per layer 256 floats: b1[64], b2[64], gamma[64], beta[64]
__global__ __launch_bounds__(256) void cvt_w_kernel(
    const void* __restrict__ W1, const void* __restrict__ b1,
    const void* __restrict__ W2, const void* __restrict__ b2,
    const void* __restrict__ g, const void* __restrict__ be,
    const int* __restrict__ flags, ushort_t* __restrict__ wp,
    float* __restrict__ bb)
{
    int i = blockIdx.x * 256 + threadIdx.x;
    int fp32 = flags[0];
    if (i < 65536) {
        int L = i >> 14;
        int r = i & 16383;
        int gg = r >> 13;
        int p = (r >> 12) & 1;
        int t4 = (r >> 10) & 3;
        int s = (r >> 9) & 1;
        int lane = (r >> 3) & 63;
        int e = r & 7;
        int k = s * 32 + (lane >> 4) * 8 + e;
        int col = t4 * 16 + (lane & 15);
        int src = L * 4096 + k * 64 + col;
        const void* W = gg ? W2 : W1;
        float v = fp32 ? ((const float*)W)[src]
                       : __bfloat162float(((const __hip_bfloat16*)W)[src]);
        __hip_bfloat16 hb = __float2bfloat16(v);
        ushort_t outv;
        if (p) {
            __hip_bfloat16 lb = __float2bfloat16(v - __bfloat162float(hb));
            outv = *(ushort_t*)&lb;
        } else {
            outv = *(ushort_t*)&hb;
        }
        wp[i] = outv;
    } else if (i < 66560) {
        int j = i - 65536;
        int L = j >> 8;
        int r = j & 255;
        int kind = r >> 6;
        int f = r & 63;
        const void* src = (kind == 0) ? b1 : (kind == 1) ? b2 : (kind == 2) ? g : be;
        int off = L * 64 + f;
        float v = fp32 ? ((const float*)src)[off]
                       : __bfloat162float(((const __hip_bfloat16*)src)[off]);
        bb[L * 256 + kind * 64 + f] = v;
    }
}

// x -> (hi, lo) bf16 pair
__global__ __launch_bounds__(256) void cvt_x_kernel(
    const void* __restrict__ x, const int* __restrict__ flags,
    ushort_t* __restrict__ zh, ushort_t* __restrict__ zl, int total)
{
    int i = blockIdx.x * 256 + threadIdx.x;
    if (i >= total) return;
    float v;
    if (flags[0]) v = ((const float*)x)[i];
    else {
        uint_t u = (uint_t)((const ushort_t*)x)[i] << 16;
        v = __uint_as_float(u);
    }
    __hip_bfloat16 hb = __float2bfloat16(v);
    __hip_bfloat16 lb = __float2bfloat16(v - __bfloat162float(hb));
    zh[i] = *(ushort_t*)&hb;
    zl[i] = *(ushort_t*)&lb;
}

// batch is SORTED: zero-atomic group offsets via boundary detection.
__global__ __launch_bounds__(256) void cvt_batch_kernel(
    const int* __restrict__ bw, const int* __restrict__ flags,
    int* __restrict__ b32, int* __restrict__ gstart, int n)
{
    int i = blockIdx.x * 256 + threadIdx.x;
    if (i >= n) return;
    int i64 = flags[2];
    int v = i64 ? bw[2 * i] : bw[i];
    b32[i] = v;
    int vn = (i + 1 < n) ? (i64 ? bw[2 * (i + 1)] : bw[i + 1]) : GG;
    if (i == 0) {
        for (int g = 0; g <= v; ++g) gstart[g] = 0;
    }
    if (vn != v) {
        for (int g = v + 1; g <= vn; ++g) gstart[g] = i + 1;
    }
}

// ---------- atomic-free CSR build (unchanged) ----------
__global__ __launch_bounds__(256) void count_hist_kernel(
    const int* __restrict__ ei, const int* __restrict__ flags,
    int* __restrict__ histo, int E)
{
    __shared__ int lh[NBK];
    int b = blockIdx.x, t = threadIdx.x;
    for (int j = t; j < NBK; j += 256) lh[j] = 0;
    __syncthreads();
    int i64 = flags[1];
    int e0 = b * ECHUNK, e1 = min(e0 + ECHUNK, E);
    for (int i = e0 + t; i < e1; i += 256) {
        int d = i64 ? ei[2 * (E + i)] : ei[E + i];
        atomicAdd(&lh[d >> 8], 1);
    }
    __syncthreads();
    for (int j = t; j < NBK; j += 256) histo[j * NHB + b] = lh[j];
}

__global__ __launch_bounds__(NHB) void blockscan_kernel(
    int* __restrict__ histo, int* __restrict__ tot)
{
    __shared__ int sd[NHB];
    int j = blockIdx.x, t = threadIdx.x;
    int v = histo[j * NHB + t];
    sd[t] = v;
    __syncthreads();
    #pragma unroll
    for (int off = 1; off < NHB; off <<= 1) {
        int add = (t >= off) ? sd[t - off] : 0;
        __syncthreads();
        sd[t] += add;
        __syncthreads();
    }
    histo[j * NHB + t] = sd[t] - v;
    if (t == NHB - 1) tot[j] = sd[NHB - 1];
}

__global__ __launch_bounds__(512) void bscan_kernel(
    const int* __restrict__ tot, int* __restrict__ bktoff)
{
    __shared__ int sd[512];
    int t = threadIdx.x;
    int v = (t < NBK) ? tot[t] : 0;
    sd[t] = v;
    __syncthreads();
    #pragma unroll
    for (int off = 1; off < 512; off <<= 1) {
        int add = (t >= off) ? sd[t - off] : 0;
        __syncthreads();
        sd[t] += add;
        __syncthreads();
    }
    if (t < NBK) bktoff[t] = sd[t] - v;
    if (t == 511) bktoff[NBK] = sd[511];
}

__global__ __launch_bounds__(256) void pair_scatter_kernel(
    const int* __restrict__ ei, const int* __restrict__ flags,
    const int* __restrict__ histo, const int* __restrict__ bktoff,
    int2* __restrict__ pairs, int E)
{
    __shared__ int cur[NBK];
    int b = blockIdx.x, t = threadIdx.x;
    for (int j = t; j < NBK; j += 256) cur[j] = histo[j * NHB + b] + bktoff[j];
    __syncthreads();
    int i64 = flags[1];
    int e0 = b * ECHUNK, e1 = min(e0 + ECHUNK, E);
    for (int i = e0 + t; i < e1; i += 256) {
        int d = i64 ? ei[2 * (E + i)] : ei[E + i];
        int s = i64 ? ei[2 * i]       : ei[i];
        int p = atomicAdd(&cur[d >> 8], 1);
        pairs[p] = make_int2(d, s);
    }
}

__global__ __launch_bounds__(256) void bucket_deg_kernel(
    const int2* __restrict__ pairs, const int* __restrict__ bktoff,
    int* __restrict__ deg, int N)
{
    __shared__ int cnt[256];
    int j = blockIdx.x, t = threadIdx.x;
    cnt[t] = 0;
    __syncthreads();
    int e0 = bktoff[j], e1 = bktoff[j + 1];
    for (int i = e0 + t; i < e1; i += 256)
        atomicAdd(&cnt[pairs[i].x & 255], 1);
    __syncthreads();
    int idx = j * 256 + t;
    if (idx < N) deg[idx] = cnt[t];
}

__global__ __launch_bounds__(256) void scan1_kernel(
    const int* __restrict__ deg, int* __restrict__ part, int* __restrict__ bsum, int n)
{
    __shared__ int sd[256];
    int t = threadIdx.x;
    int i0 = blockIdx.x * 1024 + t * 4;
    int v0 = 0, v1 = 0, v2 = 0, v3 = 0;
    if (i0 + 3 < n) {
        int4 v = *(const int4*)(deg + i0);
        v0 = v.x; v1 = v.y; v2 = v.z; v3 = v.w;
    } else if (i0 < n) {
        v0 = deg[i0];
        if (i0 + 1 < n) v1 = deg[i0 + 1];
        if (i0 + 2 < n) v2 = deg[i0 + 2];
    }
    int s = v0 + v1 + v2 + v3;
    sd[t] = s;
    __syncthreads();
    #pragma unroll
    for (int off = 1; off < 256; off <<= 1) {
        int add = (t >= off) ? sd[t - off] : 0;
        __syncthreads();
        sd[t] += add;
        __syncthreads();
    }
    int incl = sd[t];
    int e0 = incl - s;
    int p0 = e0 + v0, p1 = p0 + v1, p2 = p1 + v2, p3 = p2 + v3;
    if (i0 < n)     part[i0]     = p0;
    if (i0 + 1 < n) part[i0 + 1] = p1;
    if (i0 + 2 < n) part[i0 + 2] = p2;
    if (i0 + 3 < n) part[i0 + 3] = p3;
    if (t == 255) bsum[blockIdx.x] = incl;
}

__global__ __launch_bounds__(128) void scan2_kernel(int* __restrict__ bsum, int nb)
{
    __shared__ int sd[128];
    int t = threadIdx.x;
    int own = (t < nb) ? bsum[t] : 0;
    sd[t] = own;
    __syncthreads();
    #pragma unroll
    for (int off = 1; off < 128; off <<= 1) {
        int add = (t >= off) ? sd[t - off] : 0;
        __syncthreads();
        sd[t] += add;
        __syncthreads();
    }
    if (t < nb) bsum[t] = sd[t] - own;
}

__global__ __launch_bounds__(256) void scan3_kernel(
    const int* __restrict__ part, const int* __restrict__ bsum,
    const int* __restrict__ deg, int* __restrict__ indptr,
    float* __restrict__ inv_deg, int n)
{
    int i = blockIdx.x * 256 + threadIdx.x;
    if (i >= n) return;
    int val = part[i] + bsum[i >> 10];
    indptr[i + 1] = val;
    int d = deg[i];
    inv_deg[i] = (d > 0) ? 1.0f / (float)d : 0.0f;
    if (i == 0) indptr[0] = 0;
}

// invg from sorted-boundary gstart + identity-init of ac slot 0 (A=1, C=0)
__global__ __launch_bounds__(512) void invg_kernel(
    const int* __restrict__ gstart, float* __restrict__ invg,
    float* __restrict__ ac, int G)
{
    int g = threadIdx.x;
    if (g < G) {
        int c = gstart[g + 1] - gstart[g];
        invg[g] = (c > 0) ? 1.0f / (float)c : 0.0f;
    }
    if (g < 64) ac[g] = 1.0f;
    else if (g < 128) ac[g] = 0.0f;
}

__global__ __launch_bounds__(256) void csr_fill_kernel(
    const int2* __restrict__ pairs, const int* __restrict__ bktoff,
    const int* __restrict__ indptr, int* __restrict__ esrc, int N)
{
    __shared__ int cur[256];
    int j = blockIdx.x, t = threadIdx.x;
    int idx = j * 256 + t;
    cur[t] = (idx < N) ? indptr[idx] : 0;
    __syncthreads();
    int e0 = bktoff[j], e1 = bktoff[j + 1];
    for (int i = e0 + t; i < e1; i += 256) {
        int2 e = pairs[i];
        int p = atomicAdd(&cur[e.x & 255], 1);
        esrc[p] = e.y;
    }
}

// ---------- per-layer ----------
// agg (round-22 form + folded pool of the PREVIOUS layer):
// zout = A*(own + mean(nb)) + C*cf. If do_pool: h = A*own + C (same A,C) and
// node_pool quad rmw (first => store). rmw issued before the gather loop so it
// hides under gather latency.
__global__ __launch_bounds__(256) void agg_kernel(
    const ushort_t* __restrict__ zh_prev, const ushort_t* __restrict__ zl_prev,
    const int* __restrict__ indptr, const int* __restrict__ esrc,
    const float* __restrict__ inv_deg, const float* __restrict__ ac,
    ushort_t* __restrict__ zh_out, ushort_t* __restrict__ zl_out,
    float* __restrict__ node_pool, int do_pool, int first, int n)
{
    int t = threadIdx.x;
    int grp = t >> 4, l = t & 15;
    int lane = t & 63;
    int gl0 = lane & 48;
    int node = blockIdx.x * 16 + grp;
    if (node >= n) return;
    int e0 = indptr[node], e1 = indptr[node + 1];
    float idg = inv_deg[node];
    // own = hi + lo
    uint2 uh = *(const uint2*)(zh_prev + (size_t)node * 64 + l * 4);
    uint2 ul = *(const uint2*)(zl_prev + (size_t)node * 64 + l * 4);
    float4 own;
    own.x = __uint_as_float(uh.x << 16) + __uint_as_float(ul.x << 16);
    own.y = __uint_as_float(uh.x & 0xffff0000u) + __uint_as_float(ul.x & 0xffff0000u);
    own.z = __uint_as_float(uh.y << 16) + __uint_as_float(ul.y << 16);
    own.w = __uint_as_float(uh.y & 0xffff0000u) + __uint_as_float(ul.y & 0xffff0000u);
    float4 A = *(const float4*)(ac + l * 4);
    float4 C = *(const float4*)(ac + 64 + l * 4);

    // folded pool of the previous layer: h = A*own + C; node_pool rmw
    if (do_pool) {
        float4 h;
        h.x = fmaf(A.x, own.x, C.x);
        h.y = fmaf(A.y, own.y, C.y);
        h.z = fmaf(A.z, own.z, C.z);
        h.w = fmaf(A.w, own.w, C.w);
        float* np = node_pool + (size_t)node * 64 + l * 4;
        if (first) {
            *(float4*)np = h;
        } else {
            float4 p = *(const float4*)np;
            p.x += h.x; p.y += h.y; p.z += h.z; p.w += h.w;
            *(float4*)np = p;
        }
    }

    float a0 = 0.f, a1 = 0.f, a2 = 0.f, a3 = 0.f;
    const ushort_t* zbl = zh_prev + l * 4;

    int base = e0;
    for (; base + 16 <= e1; base += 16) {
        int myi = esrc[base + l];
        uint2 vv[16];
        #pragma unroll
        for (int j = 0; j < 16; ++j) {
            int s = __shfl(myi, gl0 + j, 64);
            vv[j] = *(const uint2*)(zbl + (size_t)s * 64);
        }
        #pragma unroll
        for (int j = 0; j < 16; ++j) {
            a0 += __uint_as_float(vv[j].x << 16);
            a1 += __uint_as_float(vv[j].x & 0xffff0000u);
            a2 += __uint_as_float(vv[j].y << 16);
            a3 += __uint_as_float(vv[j].y & 0xffff0000u);
        }
    }
    int cnt = e1 - base;
    if (cnt > 0) {
        int myi = (l < cnt) ? esrc[base + l] : 0;
        uint2 vv[16];
        #pragma unroll
        for (int j = 0; j < 16; ++j) {
            int jj = (j < cnt) ? j : 0;
            int s = __shfl(myi, gl0 + jj, 64);
            uint2 v = *(const uint2*)(zbl + (size_t)s * 64);
            vv[j].x = (j < cnt) ? v.x : 0u;
            vv[j].y = (j < cnt) ? v.y : 0u;
        }
        #pragma unroll
        for (int j = 0; j < 16; ++j) {
            a0 += __uint_as_float(vv[j].x << 16);
            a1 += __uint_as_float(vv[j].x & 0xffff0000u);
            a2 += __uint_as_float(vv[j].y << 16);
            a3 += __uint_as_float(vv[j].y & 0xffff0000u);
        }
    }

    float cf = (idg > 0.f) ? 2.f : 1.f;
    float4 r;
    r.x = fmaf(A.x, fmaf(idg, a0, own.x), C.x * cf);
    r.y = fmaf(A.y, fmaf(idg, a1, own.y), C.y * cf);
    r.z = fmaf(A.z, fmaf(idg, a2, own.z), C.z * cf);
    r.w = fmaf(A.w, fmaf(idg, a3, own.w), C.w * cf);
    // split hi/lo and store
    __hip_bfloat16 hx = __float2bfloat16(r.x);
    __hip_bfloat16 hy = __float2bfloat16(r.y);
    __hip_bfloat16 hz = __float2bfloat16(r.z);
    __hip_bfloat16 hw = __float2bfloat16(r.w);
    __hip_bfloat16 lx = __float2bfloat16(r.x - __bfloat162float(hx));
    __hip_bfloat16 ly = __float2bfloat16(r.y - __bfloat162float(hy));
    __hip_bfloat16 lz = __float2bfloat16(r.z - __bfloat162float(hz));
    __hip_bfloat16 lw = __float2bfloat16(r.w - __bfloat162float(hw));
    uint2 ph, pl;
    ph.x = (uint_t)*(ushort_t*)&hx | ((uint_t)*(ushort_t*)&hy << 16);
    ph.y = (uint_t)*(ushort_t*)&hz | ((uint_t)*(ushort_t*)&hw << 16);
    pl.x = (uint_t)*(ushort_t*)&lx | ((uint_t)*(ushort_t*)&ly << 16);
    pl.y = (uint_t)*(ushort_t*)&lz | ((uint_t)*(ushort_t*)&lw << 16);
    *(uint2*)(zh_out + (size_t)node * 64 + l * 4) = ph;
    *(uint2*)(zl_out + (size_t)node * 64 + l * 4) = pl;
}

// MLP: round-22 exact MFMA split-bf16.
__global__ __launch_bounds__(256) void mlp_kernel(
    const ushort_t* __restrict__ zh_in, const ushort_t* __restrict__ zl_in,
    const ushort_t* __restrict__ wp, const float* __restrict__ bb,
    ushort_t* __restrict__ zh_out, ushort_t* __restrict__ zl_out,
    float* __restrict__ partials, int n)
{
    __shared__ uint_t ylds[4 * 32 * YSTRIDE];
    int tid = threadIdx.x;
    int lane = tid & 63;
    int w = tid >> 6;
    int c = lane & 15, q = lane >> 4;
    int nb = blockIdx.x * 128 + w * 32;
    int wid = blockIdx.x * 4 + w;
    uint_t* my = ylds + w * 32 * YSTRIDE;

    // ---- GEMM1 ----
    #pragma unroll
    for (int mt = 0; mt < 2; ++mt) {
        int row = nb + mt * 16 + c;
        bool rv = row < n;
        bf16x8 ah0, ah1, al0, al1;
        if (rv) {
            const ushort_t* ph = zh_in + (size_t)row * 64 + q * 8;
            const ushort_t* pl = zl_in + (size_t)row * 64 + q * 8;
            ah0 = *(const bf16x8*)(ph);
            ah1 = *(const bf16x8*)(ph + 32);
            al0 = *(const bf16x8*)(pl);
            al1 = *(const bf16x8*)(pl + 32);
        } else {
            #pragma unroll
            for (int e = 0; e < 8; ++e) { ah0[e] = 0; ah1[e] = 0; al0[e] = 0; al1[e] = 0; }
        }
        f32x4 acc[4] = {{0.f,0.f,0.f,0.f},{0.f,0.f,0.f,0.f},{0.f,0.f,0.f,0.f},{0.f,0.f,0.f,0.f}};
        #pragma unroll
        for (int t4 = 0; t4 < 4; ++t4) {
            #pragma unroll
            for (int s = 0; s < 2; ++s) {
                bf16x8 bh = *(const bf16x8*)(wp + (size_t)((t4 * 2 + s) * 512) + lane * 8);
                bf16x8 bl = *(const bf16x8*)(wp + (size_t)((8 + t4 * 2 + s) * 512) + lane * 8);
                bf16x8 a_h = s ? ah1 : ah0;
                bf16x8 a_l = s ? al1 : al0;
                acc[t4] = __builtin_amdgcn_mfma_f32_16x16x32_bf16(a_l, bh, acc[t4], 0, 0, 0);
                acc[t4] = __builtin_amdgcn_mfma_f32_16x16x32_bf16(a_h, bl, acc[t4], 0, 0, 0);
                acc[t4] = __builtin_amdgcn_mfma_f32_16x16x32_bf16(a_h, bh, acc[t4], 0, 0, 0);
            }
        }
        #pragma unroll
        for (int t4 = 0; t4 < 4; ++t4) {
            float b = bb[t4 * 16 + c];
            #pragma unroll
            for (int r = 0; r < 4; ++r) {
                float y = fmaxf(acc[t4][r] + b, 0.f);
                __hip_bfloat16 hb = __float2bfloat16(y);
                __hip_bfloat16 lb = __float2bfloat16(y - __bfloat162float(hb));
                uint_t u = (uint_t)*(ushort_t*)&hb | ((uint_t)*(ushort_t*)&lb << 16);
                my[(mt * 16 + q * 4 + r) * YSTRIDE + t4 * 16 + c] = u;
            }
        }
    }
    __syncthreads();

    // ---- GEMM2 ----
    float ssum[4] = {0.f, 0.f, 0.f, 0.f};
    float ssq[4] = {0.f, 0.f, 0.f, 0.f};
    #pragma unroll
    for (int mt = 0; mt < 2; ++mt) {
        int nl = mt * 16 + c;
        bf16x8 yah[2], yal[2];
        #pragma unroll
        for (int s = 0; s < 2; ++s) {
            const uint_t* pa = my + nl * YSTRIDE + s * 32 + q * 8;
            uint4 ua = *(const uint4*)(pa);
            uint4 ub = *(const uint4*)(pa + 4);
            yah[s][0] = (short)(ua.x & 0xffffu); yal[s][0] = (short)(ua.x >> 16);
            yah[s][1] = (short)(ua.y & 0xffffu); yal[s][1] = (short)(ua.y >> 16);
            yah[s][2] = (short)(ua.z & 0xffffu); yal[s][2] = (short)(ua.z >> 16);
            yah[s][3] = (short)(ua.w & 0xffffu); yal[s][3] = (short)(ua.w >> 16);
            yah[s][4] = (short)(ub.x & 0xffffu); yal[s][4] = (short)(ub.x >> 16);
            yah[s][5] = (short)(ub.y & 0xffffu); yal[s][5] = (short)(ub.y >> 16);
            yah[s][6] = (short)(ub.z & 0xffffu); yal[s][6] = (short)(ub.z >> 16);
            yah[s][7] = (short)(ub.w & 0xffffu); yal[s][7] = (short)(ub.w >> 16);
        }
        f32x4 acc[4] = {{0.f,0.f,0.f,0.f},{0.f,0.f,0.f,0.f},{0.f,0.f,0.f,0.f},{0.f,0.f,0.f,0.f}};
        #pragma unroll
        for (int t4 = 0; t4 < 4; ++t4) {
            #pragma unroll
            for (int s = 0; s < 2; ++s) {
                bf16x8 bh = *(const bf16x8*)(wp + (size_t)((16 + t4 * 2 + s) * 512) + lane * 8);
                bf16x8 bl = *(const bf16x8*)(wp + (size_t)((24 + t4 * 2 + s) * 512) + lane * 8);
                acc[t4] = __builtin_amdgcn_mfma_f32_16x16x32_bf16(yal[s], bh, acc[t4], 0, 0, 0);
                acc[t4] = __builtin_amdgcn_mfma_f32_16x16x32_bf16(yah[s], bl, acc[t4], 0, 0, 0);
                acc[t4] = __builtin_amdgcn_mfma_f32_16x16x32_bf16(yah[s], bh, acc[t4], 0, 0, 0);
            }
        }
        #pragma unroll
        for (int t4 = 0; t4 < 4; ++t4) {
            float b = bb[64 + t4 * 16 + c];
            #pragma unroll
            for (int r = 0; r < 4; ++r) {
                int node = nb + mt * 16 + q * 4 + r;
                float h = fmaxf(acc[t4][r] + b, 0.f);
                float hv = (node < n) ? h : 0.f;
                ssum[t4] += hv;
                ssq[t4] += hv * hv;
                my[(mt * 16 + q * 4 + r) * YSTRIDE + t4 * 16 + c] = __float_as_uint(h);
            }
        }
    }
    __syncthreads();

    // stats butterfly across the 4 quadrants (rows); lanes 0..15 store
    #pragma unroll
    for (int t4 = 0; t4 < 4; ++t4) {
        ssum[t4] += __shfl_xor(ssum[t4], 16, 64);
        ssum[t4] += __shfl_xor(ssum[t4], 32, 64);
        ssq[t4]  += __shfl_xor(ssq[t4], 16, 64);
        ssq[t4]  += __shfl_xor(ssq[t4], 32, 64);
    }
    if (lane < 16) {
        #pragma unroll
        for (int t4 = 0; t4 < 4; ++t4) {
            partials[(size_t)(t4 * 16 + lane) * NWAVE + wid] = ssum[t4];
            partials[(size_t)(64 + t4 * 16 + lane) * NWAVE + wid] = ssq[t4];
        }
    }

    // store phase: coalesced (zh, zl) from LDS h
    #pragma unroll
    for (int cc = 0; cc < 8; ++cc) {
        int li = lane + 64 * cc;
        int nl = li >> 4, fg = li & 15;
        int node = nb + nl;
        if (node < n) {
            uint4 u = *(const uint4*)(my + nl * YSTRIDE + fg * 4);
            float f0 = __uint_as_float(u.x);
            float f1 = __uint_as_float(u.y);
            float f2 = __uint_as_float(u.z);
            float f3 = __uint_as_float(u.w);
            __hip_bfloat16 h0 = __float2bfloat16(f0);
            __hip_bfloat16 h1 = __float2bfloat16(f1);
            __hip_bfloat16 h2 = __float2bfloat16(f2);
            __hip_bfloat16 h3 = __float2bfloat16(f3);
            __hip_bfloat16 l0 = __float2bfloat16(f0 - __bfloat162float(h0));
            __hip_bfloat16 l1 = __float2bfloat16(f1 - __bfloat162float(h1));
            __hip_bfloat16 l2 = __float2bfloat16(f2 - __bfloat162float(h2));
            __hip_bfloat16 l3 = __float2bfloat16(f3 - __bfloat162float(h3));
            uint2 ph, pl;
            ph.x = (uint_t)*(ushort_t*)&h0 | ((uint_t)*(ushort_t*)&h1 << 16);
            ph.y = (uint_t)*(ushort_t*)&h2 | ((uint_t)*(ushort_t*)&h3 << 16);
            pl.x = (uint_t)*(ushort_t*)&l0 | ((uint_t)*(ushort_t*)&l1 << 16);
            pl.y = (uint_t)*(ushort_t*)&l2 | ((uint_t)*(ushort_t*)&l3 << 16);
            *(uint2*)(zh_out + (size_t)node * 64 + fg * 4) = ph;
            *(uint2*)(zl_out + (size_t)node * 64 + fg * 4) = pl;
        }
    }
}

// reduce per-wave partials -> BN affine (A,C) for this layer's ac slot.
__global__ __launch_bounds__(256) void redstats_kernel(
    const float* __restrict__ partials, const float* __restrict__ gammaf,
    const float* __restrict__ betaf, float* __restrict__ ac_out)
{
    __shared__ float s1[256], s2[256];
    int f = blockIdx.x;
    int t = threadIdx.x;
    const float* ph = partials + (size_t)f * NWAVE;
    const float* pq = partials + (size_t)(64 + f) * NWAVE;
    float a = 0.f, b = 0.f;
    for (int i = t; i < NWAVE; i += 256) { a += ph[i]; b += pq[i]; }
    s1[t] = a; s2[t] = b;
    __syncthreads();
    for (int off = 128; off > 0; off >>= 1) {
        if (t < off) { s1[t] += s1[t + off]; s2[t] += s2[t + off]; }
        __syncthreads();
    }
    if (t == 0) {
        const float invN = 1.0f / (float)NN;
        float mu = s1[0] * invN;
        float var = s2[0] * invN - mu * mu;
        if (var < 0.f) var = 0.f;
        float A = gammaf[f] * rsqrtf(var + 1e-5f);
        float C = betaf[f] - mu * A;
        ac_out[f] = A;
        ac_out[64 + f] = C;
    }
}

// final pool (layer 3 only): p = node_pool + (A*z+C); out node section = p;
// gpool = run-length segsum of p (== segsum(node_pool_final), linearity).
__global__ __launch_bounds__(256) void pool_kernel(
    const ushort_t* __restrict__ zh, const ushort_t* __restrict__ zl,
    const float* __restrict__ node_pool, const int* __restrict__ b32,
    const float* __restrict__ ac, float* __restrict__ gpool,
    const int* __restrict__ flags, void* __restrict__ out, int N)
{
    int wave = (blockIdx.x * 256 + threadIdx.x) >> 6;
    int f = threadIdx.x & 63;
    int n0 = wave * 16;
    if (n0 >= N) return;
    int n1 = min(n0 + 16, N);
    float A = ac[f], C = ac[64 + f];
    int fp32 = flags[0];
    float racc = 0.f;
    int cur = b32[n0];
    int n = n0;
    for (; n + 4 <= n1; n += 4) {
        int4 gv = *(const int4*)(b32 + n);
        size_t idx = (size_t)n * 64 + f;
        float z0 = __uint_as_float((uint_t)zh[idx] << 16)       + __uint_as_float((uint_t)zl[idx] << 16);
        float z1 = __uint_as_float((uint_t)zh[idx + 64] << 16)  + __uint_as_float((uint_t)zl[idx + 64] << 16);
        float z2 = __uint_as_float((uint_t)zh[idx + 128] << 16) + __uint_as_float((uint_t)zl[idx + 128] << 16);
        float z3 = __uint_as_float((uint_t)zh[idx + 192] << 16) + __uint_as_float((uint_t)zl[idx + 192] << 16);
        float p0 = node_pool[idx]       + fmaf(z0, A, C);
        float p1 = node_pool[idx + 64]  + fmaf(z1, A, C);
        float p2 = node_pool[idx + 128] + fmaf(z2, A, C);
        float p3 = node_pool[idx + 192] + fmaf(z3, A, C);
        if (fp32) {
            ((float*)out)[idx]       = p0;
            ((float*)out)[idx + 64]  = p1;
            ((float*)out)[idx + 128] = p2;
            ((float*)out)[idx + 192] = p3;
        } else {
            __hip_bfloat16 b0 = __float2bfloat16(p0);
            __hip_bfloat16 b1 = __float2bfloat16(p1);
            __hip_bfloat16 b2 = __float2bfloat16(p2);
            __hip_bfloat16 b3 = __float2bfloat16(p3);
            ((__hip_bfloat16*)out)[idx]       = b0;
            ((__hip_bfloat16*)out)[idx + 64]  = b1;
            ((__hip_bfloat16*)out)[idx + 128] = b2;
            ((__hip_bfloat16*)out)[idx + 192] = b3;
        }
        int gs0 = gv.x, gs1 = gv.y, gs2 = gv.z, gs3 = gv.w;
        if (gs0 != cur) { atomicAdd(&gpool[(size_t)cur * 64 + f], racc); racc = 0.f; cur = gs0; }
        racc += p0;
        if (gs1 != cur) { atomicAdd(&gpool[(size_t)cur * 64 + f], racc); racc = 0.f; cur = gs1; }
        racc += p1;
        if (gs2 != cur) { atomicAdd(&gpool[(size_t)cur * 64 + f], racc); racc = 0.f; cur = gs2; }
        racc += p2;
        if (gs3 != cur) { atomicAdd(&gpool[(size_t)cur * 64 + f], racc); racc = 0.f; cur = gs3; }
        racc += p3;
    }
    for (; n < n1; ++n) {  // tail (unused when 16 | N; kept for safety)
        int g = b32[n];
        if (g != cur) { atomicAdd(&gpool[(size_t)cur * 64 + f], racc); racc = 0.f; cur = g; }
        size_t idx = (size_t)n * 64 + f;
        float zv = __uint_as_float((uint_t)zh[idx] << 16) + __uint_as_float((uint_t)zl[idx] << 16);
        float p = node_pool[idx] + fmaf(zv, A, C);
        if (fp32) ((float*)out)[idx] = p;
        else ((__hip_bfloat16*)out)[idx] = __float2bfloat16(p);
        racc += p;
    }
    atomicAdd(&gpool[(size_t)cur * 64 + f], racc);
}

// finalize: gpool tail only (node section written by pool)
__global__ __launch_bounds__(256) void finalize_kernel(
    const float* __restrict__ gpool, const float* __restrict__ invg,
    const int* __restrict__ flags, void* __restrict__ out, int N)
{
    int i = blockIdx.x * 256 + threadIdx.x;
    if (i >= GG * 64) return;
    float v = gpool[i] * invg[i >> 6];
    int nd = N * 64;
    if (flags[0]) ((float*)out)[nd + i] = v;
    else ((__hip_bfloat16*)out)[nd + i] = __float2bfloat16(v);
}

extern "C" void kernel_launch(void* const* d_in, const int* in_sizes, int n_in,
                              void* d_out, int out_size, void* d_ws, size_t ws_size,
                              hipStream_t stream)
{
    constexpr int N = NN, E = EE, G = GG;
    constexpr int ND = N * 64;

    const void* x     = d_in[0];
    const void* W1    = d_in[1];
    const void* b1    = d_in[2];
    const void* W2    = d_in[3];
    const void* b2    = d_in[4];
    const void* gamma = d_in[5];
    const void* beta  = d_in[6];
    const int* ei     = (const int*)d_in[7];
    const int* batw   = (const int*)d_in[8];

    char* p = (char*)d_ws;
    auto alloc = [&](size_t bytes) -> char* {
        char* r = p;
        p += (bytes + 255) & ~(size_t)255;
        return r;
    };
    ushort_t* zhA      = (ushort_t*)alloc((size_t)ND * 2);
    ushort_t* zlA      = (ushort_t*)alloc((size_t)ND * 2);
    ushort_t* zhB      = (ushort_t*)alloc((size_t)ND * 2);
    ushort_t* zlB      = (ushort_t*)alloc((size_t)ND * 2);
    float*    node_pool = (float*)alloc((size_t)ND * 4);
    int*      esrc      = (int*)alloc((size_t)E * 4);
    int*      indptr    = (int*)alloc((size_t)(N + 1) * 4);
    int*      deg       = (int*)alloc((size_t)N * 4);
    int*      part      = (int*)alloc((size_t)N * 4);
    float*    invdeg    = (float*)alloc((size_t)N * 4);
    int*      b32       = (int*)alloc((size_t)N * 4);
    int*      bsum      = (int*)alloc(128 * 4);
    int*      gstart    = (int*)alloc((size_t)(G + 1) * 4);
    float*    invg      = (float*)alloc(G * 4);
    float*    gpool     = (float*)alloc((size_t)G * 64 * 4);
    float*    ac5       = (float*)alloc(5 * 128 * 4);  // slot0 identity, slots1..4 BN_l
    float*    partials  = (float*)alloc((size_t)128 * NWAVE * 4);  // 1.6 MB
    ushort_t* wp        = (ushort_t*)alloc((size_t)4 * 16384 * 2); // packed weights
    float*    bb        = (float*)alloc(4 * 256 * 4);  // b1,b2,gamma,beta per layer
    int*      flags     = (int*)alloc(16 * 4);
    int*      histo     = (int*)alloc((size_t)NBK * NHB * 4);
    int*      tot       = (int*)alloc((size_t)NBK * 4);
    int*      bktoff    = (int*)alloc((size_t)(NBK + 1) * 4);
    // pairs aliases node_pool: dead until agg_1's folded pool; E*8 == ND*4 bytes
    int2*     pairs     = (int2*)node_pool;

    hipMemsetAsync(gpool, 0, (size_t)G * 64 * 4, stream);

    detect_kernel<<<1, 256, 0, stream>>>(
        (const uint_t*)x, (const uint_t*)ei, (const uint_t*)batw, flags);
    cvt_w_kernel<<<260, 256, 0, stream>>>(W1, b1, W2, b2, gamma, beta, flags, wp, bb);
    cvt_x_kernel<<<(ND + 255) / 256, 256, 0, stream>>>(x, flags, zhA, zlA, ND);
    cvt_batch_kernel<<<(N + 255) / 256, 256, 0, stream>>>(batw, flags, b32, gstart, N);
    count_hist_kernel<<<NHB, 256, 0, stream>>>(ei, flags, histo, E);
    blockscan_kernel<<<NBK, NHB, 0, stream>>>(histo, tot);
    bscan_kernel<<<1, 512, 0, stream>>>(tot, bktoff);
    pair_scatter_kernel<<<NHB, 256, 0, stream>>>(ei, flags, histo, bktoff, pairs, E);
    bucket_deg_kernel<<<NBK, 256, 0, stream>>>(pairs, bktoff, deg, N);
    int nb = (N + 1023) / 1024;  // 98
    scan1_kernel<<<nb, 256, 0, stream>>>(deg, part, bsum, N);
    scan2_kernel<<<1, 128, 0, stream>>>(bsum, nb);
    scan3_kernel<<<(N + 255) / 256, 256, 0, stream>>>(part, bsum, deg, indptr, invdeg, N);
    invg_kernel<<<1, 512, 0, stream>>>(gstart, invg, ac5, G);
    csr_fill_kernel<<<NBK, 256, 0, stream>>>(pairs, bktoff, indptr, esrc, N);

    for (int l = 0; l < 4; ++l) {
        // agg layer l consumes ac slot l; for l>=1 it also executes pool of
        // layer l-1 (same slot) via node_pool rmw. pairs (aliasing node_pool)
        // is dead by the time agg_1 runs.
        agg_kernel<<<(N + 15) / 16, 256, 0, stream>>>(
            zhA, zlA, indptr, esrc, invdeg, ac5 + l * 128,
            zhB, zlB, node_pool, (l >= 1) ? 1 : 0, (l == 1) ? 1 : 0, N);
        mlp_kernel<<<MLPBLOCKS, 256, 0, stream>>>(
            zhB, zlB, wp + (size_t)l * 16384, bb + l * 256,
            zhA, zlA, partials, N);
        redstats_kernel<<<64, 256, 0, stream>>>(
            partials, bb + l * 256 + 128, bb + l * 256 + 192,
            ac5 + (l + 1) * 128);
    }
    // final pool: p = node_pool + h_3; out node section = p; gpool = segsum(p)
    pool_kernel<<<(N + 63) / 64, 256, 0, stream>>>(
        zhA, zlA, node_pool, b32, ac5 + 4 * 128, gpool, flags, d_out, N);
    finalize_kernel<<<128, 256, 0, stream>>>(gpool, invg, flags, d_out, N);
}

// Round 16
// 571.412 us; speedup vs baseline: 1.0643x; 1.0138x over previous
//
#include <hip/hip_runtime.h>
#include <hip/hip_bf16.h>

// GIN_34789235098229 — round 25: mlp slim — planar y-LDS (no unpack) + B hi-only.
// Round 24 = 579.3us (best; agg 63.5 incl folded pool, as predicted). Budget
// arithmetic: mlp x4 ~ 225us residual (~50us each, just under agg's top-5
// cutoff) vs ~13us streaming floor => best lever. (a) y stored in LDS as
// separate hi/lo bf16 planes per row (64+64 ushorts, same 68-uint stride):
// GEMM2 A-fragments become direct 16B bf16x8 loads, zero unpack VALU —
// bit-identical. (b) B-fragments hi-only: (ah+al)*bh = 2 MFMAs/slot (was 3).
// Input side keeps full hi+lo; only the WEIGHT lo correction (~0.4% of W) is
// dropped => ~0.005 absolute error, 25x below the 0.125 bf16-output-rounding
// floor. MFMA 96->64, B-loads halved. Everything else unchanged from round 24.

typedef unsigned short ushort_t;
typedef unsigned int uint_t;
typedef __attribute__((ext_vector_type(8))) short bf16x8;
typedef __attribute__((ext_vector_type(4))) float f32x4;

#define NN 100000
#define EE 3200000
#define GG 512
#define NBK 391    // ceil(NN/256); bucket = node >> 8
#define NHB 256    // histogram blocks
#define ECHUNK 12500  // EE / NHB exactly
#define MLPBLOCKS 782        // ceil(NN / 128 nodes-per-block)
#define NWAVE (MLPBLOCKS * 4)  // 3128 wave slots for stats partials
#define YSTRIDE 68   // LDS row stride in uints (136 ushorts: 64 hi + 64 lo + pad)

// ---------- detection ----------
__global__ __launch_bounds__(256) void detect_kernel(
    const uint_t* __restrict__ xw, const uint_t* __restrict__ ew,
    const uint_t* __restrict__ bw, int* __restrict__ flags)
{
    __shared__ int sb[256], se[256], sbb[256];
    int t = threadIdx.x;
    uint_t w = xw[t];
    uint_t eL = (w >> 7) & 0xffu;
    sb[t] = (eL >= 112u && eL <= 135u) ? 1 : 0;
    se[t] = (ew[2 * t + 1] == 0u) ? 1 : 0;
    sbb[t] = (bw[NN - 512 + 2 * t + 1] == 0u) ? 1 : 0;
    __syncthreads();
    for (int off = 128; off > 0; off >>= 1) {
        if (t < off) { sb[t] += sb[t + off]; se[t] += se[t + off]; sbb[t] += sbb[t + off]; }
        __syncthreads();
    }
    if (t == 0) {
        flags[0] = (sb[0] < 128) ? 1 : 0;   // 1 => fp32 floats
        flags[1] = (se[0] >= 128) ? 1 : 0;  // 1 => int64 edges
        flags[2] = (sbb[0] >= 128) ? 1 : 0; // 1 => int64 batch
    }
}

// ---------- canonicalization ----------
// wp: packed MFMA B-fragments, per layer 16384 ushorts (see round 22).
// bb: per layer 256 floats: b1[64], b2[64], gamma[64], beta[64]
__global__ __launch_bounds__(256) void cvt_w_kernel(
    const void* __restrict__ W1, const void* __restrict__ b1,
    const void* __restrict__ W2, const void* __restrict__ b2,
    const void* __restrict__ g, const void* __restrict__ be,
    const int* __restrict__ flags, ushort_t* __restrict__ wp,
    float* __restrict__ bb)
{
    int i = blockIdx.x * 256 + threadIdx.x;
    int fp32 = flags[0];
    if (i < 65536) {
        int L = i >> 14;
        int r = i & 16383;
        int gg = r >> 13;
        int p = (r >> 12) & 1;
        int t4 = (r >> 10) & 3;
        int s = (r >> 9) & 1;
        int lane = (r >> 3) & 63;
        int e = r & 7;
        int k = s * 32 + (lane >> 4) * 8 + e;
        int col = t4 * 16 + (lane & 15);
        int src = L * 4096 + k * 64 + col;
        const void* W = gg ? W2 : W1;
        float v = fp32 ? ((const float*)W)[src]
                       : __bfloat162float(((const __hip_bfloat16*)W)[src]);
        __hip_bfloat16 hb = __float2bfloat16(v);
        ushort_t outv;
        if (p) {
            __hip_bfloat16 lb = __float2bfloat16(v - __bfloat162float(hb));
            outv = *(ushort_t*)&lb;
        } else {
            outv = *(ushort_t*)&hb;
        }
        wp[i] = outv;
    } else if (i < 66560) {
        int j = i - 65536;
        int L = j >> 8;
        int r = j & 255;
        int kind = r >> 6;
        int f = r & 63;
        const void* src = (kind == 0) ? b1 : (kind == 1) ? b2 : (kind == 2) ? g : be;
        int off = L * 64 + f;
        float v = fp32 ? ((const float*)src)[off]
                       : __bfloat162float(((const __hip_bfloat16*)src)[off]);
        bb[L * 256 + kind * 64 + f] = v;
    }
}

// x -> (hi, lo) bf16 pair
__global__ __launch_bounds__(256) void cvt_x_kernel(
    const void* __restrict__ x, const int* __restrict__ flags,
    ushort_t* __restrict__ zh, ushort_t* __restrict__ zl, int total)
{
    int i = blockIdx.x * 256 + threadIdx.x;
    if (i >= total) return;
    float v;
    if (flags[0]) v = ((const float*)x)[i];
    else {
        uint_t u = (uint_t)((const ushort_t*)x)[i] << 16;
        v = __uint_as_float(u);
    }
    __hip_bfloat16 hb = __float2bfloat16(v);
    __hip_bfloat16 lb = __float2bfloat16(v - __bfloat162float(hb));
    zh[i] = *(ushort_t*)&hb;
    zl[i] = *(ushort_t*)&lb;
}

// batch is SORTED: zero-atomic group offsets via boundary detection.
__global__ __launch_bounds__(256) void cvt_batch_kernel(
    const int* __restrict__ bw, const int* __restrict__ flags,
    int* __restrict__ b32, int* __restrict__ gstart, int n)
{
    int i = blockIdx.x * 256 + threadIdx.x;
    if (i >= n) return;
    int i64 = flags[2];
    int v = i64 ? bw[2 * i] : bw[i];
    b32[i] = v;
    int vn = (i + 1 < n) ? (i64 ? bw[2 * (i + 1)] : bw[i + 1]) : GG;
    if (i == 0) {
        for (int g = 0; g <= v; ++g) gstart[g] = 0;
    }
    if (vn != v) {
        for (int g = v + 1; g <= vn; ++g) gstart[g] = i + 1;
    }
}

// ---------- atomic-free CSR build (unchanged) ----------
__global__ __launch_bounds__(256) void count_hist_kernel(
    const int* __restrict__ ei, const int* __restrict__ flags,
    int* __restrict__ histo, int E)
{
    __shared__ int lh[NBK];
    int b = blockIdx.x, t = threadIdx.x;
    for (int j = t; j < NBK; j += 256) lh[j] = 0;
    __syncthreads();
    int i64 = flags[1];
    int e0 = b * ECHUNK, e1 = min(e0 + ECHUNK, E);
    for (int i = e0 + t; i < e1; i += 256) {
        int d = i64 ? ei[2 * (E + i)] : ei[E + i];
        atomicAdd(&lh[d >> 8], 1);
    }
    __syncthreads();
    for (int j = t; j < NBK; j += 256) histo[j * NHB + b] = lh[j];
}

__global__ __launch_bounds__(NHB) void blockscan_kernel(
    int* __restrict__ histo, int* __restrict__ tot)
{
    __shared__ int sd[NHB];
    int j = blockIdx.x, t = threadIdx.x;
    int v = histo[j * NHB + t];
    sd[t] = v;
    __syncthreads();
    #pragma unroll
    for (int off = 1; off < NHB; off <<= 1) {
        int add = (t >= off) ? sd[t - off] : 0;
        __syncthreads();
        sd[t] += add;
        __syncthreads();
    }
    histo[j * NHB + t] = sd[t] - v;
    if (t == NHB - 1) tot[j] = sd[NHB - 1];
}

__global__ __launch_bounds__(512) void bscan_kernel(
    const int* __restrict__ tot, int* __restrict__ bktoff)
{
    __shared__ int sd[512];
    int t = threadIdx.x;
    int v = (t < NBK) ? tot[t] : 0;
    sd[t] = v;
    __syncthreads();
    #pragma unroll
    for (int off = 1; off < 512; off <<= 1) {
        int add = (t >= off) ? sd[t - off] : 0;
        __syncthreads();
        sd[t] += add;
        __syncthreads();
    }
    if (t < NBK) bktoff[t] = sd[t] - v;
    if (t == 511) bktoff[NBK] = sd[511];
}

__global__ __launch_bounds__(256) void pair_scatter_kernel(
    const int* __restrict__ ei, const int* __restrict__ flags,
    const int* __restrict__ histo, const int* __restrict__ bktoff,
    int2* __restrict__ pairs, int E)
{
    __shared__ int cur[NBK];
    int b = blockIdx.x, t = threadIdx.x;
    for (int j = t; j < NBK; j += 256) cur[j] = histo[j * NHB + b] + bktoff[j];
    __syncthreads();
    int i64 = flags[1];
    int e0 = b * ECHUNK, e1 = min(e0 + ECHUNK, E);
    for (int i = e0 + t; i < e1; i += 256) {
        int d = i64 ? ei[2 * (E + i)] : ei[E + i];
        int s = i64 ? ei[2 * i]       : ei[i];
        int p = atomicAdd(&cur[d >> 8], 1);
        pairs[p] = make_int2(d, s);
    }
}

__global__ __launch_bounds__(256) void bucket_deg_kernel(
    const int2* __restrict__ pairs, const int* __restrict__ bktoff,
    int* __restrict__ deg, int N)
{
    __shared__ int cnt[256];
    int j = blockIdx.x, t = threadIdx.x;
    cnt[t] = 0;
    __syncthreads();
    int e0 = bktoff[j], e1 = bktoff[j + 1];
    for (int i = e0 + t; i < e1; i += 256)
        atomicAdd(&cnt[pairs[i].x & 255], 1);
    __syncthreads();
    int idx = j * 256 + t;
    if (idx < N) deg[idx] = cnt[t];
}

__global__ __launch_bounds__(256) void scan1_kernel(
    const int* __restrict__ deg, int* __restrict__ part, int* __restrict__ bsum, int n)
{
    __shared__ int sd[256];
    int t = threadIdx.x;
    int i0 = blockIdx.x * 1024 + t * 4;
    int v0 = 0, v1 = 0, v2 = 0, v3 = 0;
    if (i0 + 3 < n) {
        int4 v = *(const int4*)(deg + i0);
        v0 = v.x; v1 = v.y; v2 = v.z; v3 = v.w;
    } else if (i0 < n) {
        v0 = deg[i0];
        if (i0 + 1 < n) v1 = deg[i0 + 1];
        if (i0 + 2 < n) v2 = deg[i0 + 2];
    }
    int s = v0 + v1 + v2 + v3;
    sd[t] = s;
    __syncthreads();
    #pragma unroll
    for (int off = 1; off < 256; off <<= 1) {
        int add = (t >= off) ? sd[t - off] : 0;
        __syncthreads();
        sd[t] += add;
        __syncthreads();
    }
    int incl = sd[t];
    int e0 = incl - s;
    int p0 = e0 + v0, p1 = p0 + v1, p2 = p1 + v2, p3 = p2 + v3;
    if (i0 < n)     part[i0]     = p0;
    if (i0 + 1 < n) part[i0 + 1] = p1;
    if (i0 + 2 < n) part[i0 + 2] = p2;
    if (i0 + 3 < n) part[i0 + 3] = p3;
    if (t == 255) bsum[blockIdx.x] = incl;
}

__global__ __launch_bounds__(128) void scan2_kernel(int* __restrict__ bsum, int nb)
{
    __shared__ int sd[128];
    int t = threadIdx.x;
    int own = (t < nb) ? bsum[t] : 0;
    sd[t] = own;
    __syncthreads();
    #pragma unroll
    for (int off = 1; off < 128; off <<= 1) {
        int add = (t >= off) ? sd[t - off] : 0;
        __syncthreads();
        sd[t] += add;
        __syncthreads();
    }
    if (t < nb) bsum[t] = sd[t] - own;
}

__global__ __launch_bounds__(256) void scan3_kernel(
    const int* __restrict__ part, const int* __restrict__ bsum,
    const int* __restrict__ deg, int* __restrict__ indptr,
    float* __restrict__ inv_deg, int n)
{
    int i = blockIdx.x * 256 + threadIdx.x;
    if (i >= n) return;
    int val = part[i] + bsum[i >> 10];
    indptr[i + 1] = val;
    int d = deg[i];
    inv_deg[i] = (d > 0) ? 1.0f / (float)d : 0.0f;
    if (i == 0) indptr[0] = 0;
}

// invg from sorted-boundary gstart + identity-init of ac slot 0 (A=1, C=0)
__global__ __launch_bounds__(512) void invg_kernel(
    const int* __restrict__ gstart, float* __restrict__ invg,
    float* __restrict__ ac, int G)
{
    int g = threadIdx.x;
    if (g < G) {
        int c = gstart[g + 1] - gstart[g];
        invg[g] = (c > 0) ? 1.0f / (float)c : 0.0f;
    }
    if (g < 64) ac[g] = 1.0f;
    else if (g < 128) ac[g] = 0.0f;
}

__global__ __launch_bounds__(256) void csr_fill_kernel(
    const int2* __restrict__ pairs, const int* __restrict__ bktoff,
    const int* __restrict__ indptr, int* __restrict__ esrc, int N)
{
    __shared__ int cur[256];
    int j = blockIdx.x, t = threadIdx.x;
    int idx = j * 256 + t;
    cur[t] = (idx < N) ? indptr[idx] : 0;
    __syncthreads();
    int e0 = bktoff[j], e1 = bktoff[j + 1];
    for (int i = e0 + t; i < e1; i += 256) {
        int2 e = pairs[i];
        int p = atomicAdd(&cur[e.x & 255], 1);
        esrc[p] = e.y;
    }
}

// ---------- per-layer ----------
// agg (round-24 form, unchanged): zout = A*(own + mean(nb)) + C*cf.
// If do_pool: h = A*own + C and node_pool quad rmw (hidden under gather).
__global__ __launch_bounds__(256) void agg_kernel(
    const ushort_t* __restrict__ zh_prev, const ushort_t* __restrict__ zl_prev,
    const int* __restrict__ indptr, const int* __restrict__ esrc,
    const float* __restrict__ inv_deg, const float* __restrict__ ac,
    ushort_t* __restrict__ zh_out, ushort_t* __restrict__ zl_out,
    float* __restrict__ node_pool, int do_pool, int first, int n)
{
    int t = threadIdx.x;
    int grp = t >> 4, l = t & 15;
    int lane = t & 63;
    int gl0 = lane & 48;
    int node = blockIdx.x * 16 + grp;
    if (node >= n) return;
    int e0 = indptr[node], e1 = indptr[node + 1];
    float idg = inv_deg[node];
    // own = hi + lo
    uint2 uh = *(const uint2*)(zh_prev + (size_t)node * 64 + l * 4);
    uint2 ul = *(const uint2*)(zl_prev + (size_t)node * 64 + l * 4);
    float4 own;
    own.x = __uint_as_float(uh.x << 16) + __uint_as_float(ul.x << 16);
    own.y = __uint_as_float(uh.x & 0xffff0000u) + __uint_as_float(ul.x & 0xffff0000u);
    own.z = __uint_as_float(uh.y << 16) + __uint_as_float(ul.y << 16);
    own.w = __uint_as_float(uh.y & 0xffff0000u) + __uint_as_float(ul.y & 0xffff0000u);
    float4 A = *(const float4*)(ac + l * 4);
    float4 C = *(const float4*)(ac + 64 + l * 4);

    // folded pool of the previous layer: h = A*own + C; node_pool rmw
    if (do_pool) {
        float4 h;
        h.x = fmaf(A.x, own.x, C.x);
        h.y = fmaf(A.y, own.y, C.y);
        h.z = fmaf(A.z, own.z, C.z);
        h.w = fmaf(A.w, own.w, C.w);
        float* np = node_pool + (size_t)node * 64 + l * 4;
        if (first) {
            *(float4*)np = h;
        } else {
            float4 p = *(const float4*)np;
            p.x += h.x; p.y += h.y; p.z += h.z; p.w += h.w;
            *(float4*)np = p;
        }
    }

    float a0 = 0.f, a1 = 0.f, a2 = 0.f, a3 = 0.f;
    const ushort_t* zbl = zh_prev + l * 4;

    int base = e0;
    for (; base + 16 <= e1; base += 16) {
        int myi = esrc[base + l];
        uint2 vv[16];
        #pragma unroll
        for (int j = 0; j < 16; ++j) {
            int s = __shfl(myi, gl0 + j, 64);
            vv[j] = *(const uint2*)(zbl + (size_t)s * 64);
        }
        #pragma unroll
        for (int j = 0; j < 16; ++j) {
            a0 += __uint_as_float(vv[j].x << 16);
            a1 += __uint_as_float(vv[j].x & 0xffff0000u);
            a2 += __uint_as_float(vv[j].y << 16);
            a3 += __uint_as_float(vv[j].y & 0xffff0000u);
        }
    }
    int cnt = e1 - base;
    if (cnt > 0) {
        int myi = (l < cnt) ? esrc[base + l] : 0;
        uint2 vv[16];
        #pragma unroll
        for (int j = 0; j < 16; ++j) {
            int jj = (j < cnt) ? j : 0;
            int s = __shfl(myi, gl0 + jj, 64);
            uint2 v = *(const uint2*)(zbl + (size_t)s * 64);
            vv[j].x = (j < cnt) ? v.x : 0u;
            vv[j].y = (j < cnt) ? v.y : 0u;
        }
        #pragma unroll
        for (int j = 0; j < 16; ++j) {
            a0 += __uint_as_float(vv[j].x << 16);
            a1 += __uint_as_float(vv[j].x & 0xffff0000u);
            a2 += __uint_as_float(vv[j].y << 16);
            a3 += __uint_as_float(vv[j].y & 0xffff0000u);
        }
    }

    float cf = (idg > 0.f) ? 2.f : 1.f;
    float4 r;
    r.x = fmaf(A.x, fmaf(idg, a0, own.x), C.x * cf);
    r.y = fmaf(A.y, fmaf(idg, a1, own.y), C.y * cf);
    r.z = fmaf(A.z, fmaf(idg, a2, own.z), C.z * cf);
    r.w = fmaf(A.w, fmaf(idg, a3, own.w), C.w * cf);
    // split hi/lo and store
    __hip_bfloat16 hx = __float2bfloat16(r.x);
    __hip_bfloat16 hy = __float2bfloat16(r.y);
    __hip_bfloat16 hz = __float2bfloat16(r.z);
    __hip_bfloat16 hw = __float2bfloat16(r.w);
    __hip_bfloat16 lx = __float2bfloat16(r.x - __bfloat162float(hx));
    __hip_bfloat16 ly = __float2bfloat16(r.y - __bfloat162float(hy));
    __hip_bfloat16 lz = __float2bfloat16(r.z - __bfloat162float(hz));
    __hip_bfloat16 lw = __float2bfloat16(r.w - __bfloat162float(hw));
    uint2 ph, pl;
    ph.x = (uint_t)*(ushort_t*)&hx | ((uint_t)*(ushort_t*)&hy << 16);
    ph.y = (uint_t)*(ushort_t*)&hz | ((uint_t)*(ushort_t*)&hw << 16);
    pl.x = (uint_t)*(ushort_t*)&lx | ((uint_t)*(ushort_t*)&ly << 16);
    pl.y = (uint_t)*(ushort_t*)&lz | ((uint_t)*(ushort_t*)&lw << 16);
    *(uint2*)(zh_out + (size_t)node * 64 + l * 4) = ph;
    *(uint2*)(zl_out + (size_t)node * 64 + l * 4) = pl;
}

// MLP round 25: MFMA, B hi-only (2 mfma/slot), planar y-LDS (no unpack).
__global__ __launch_bounds__(256) void mlp_kernel(
    const ushort_t* __restrict__ zh_in, const ushort_t* __restrict__ zl_in,
    const ushort_t* __restrict__ wp, const float* __restrict__ bb,
    ushort_t* __restrict__ zh_out, ushort_t* __restrict__ zl_out,
    float* __restrict__ partials, int n)
{
    __shared__ uint_t ylds[4 * 32 * YSTRIDE];
    int tid = threadIdx.x;
    int lane = tid & 63;
    int w = tid >> 6;
    int c = lane & 15, q = lane >> 4;
    int nb = blockIdx.x * 128 + w * 32;
    int wid = blockIdx.x * 4 + w;
    uint_t* my = ylds + w * 32 * YSTRIDE;
    ushort_t* mys = (ushort_t*)my;     // row stride 136 ushorts: [0,64) hi, [64,128) lo

    // ---- GEMM1 ----
    #pragma unroll
    for (int mt = 0; mt < 2; ++mt) {
        int row = nb + mt * 16 + c;
        bool rv = row < n;
        bf16x8 ah0, ah1, al0, al1;
        if (rv) {
            const ushort_t* ph = zh_in + (size_t)row * 64 + q * 8;
            const ushort_t* pl = zl_in + (size_t)row * 64 + q * 8;
            ah0 = *(const bf16x8*)(ph);
            ah1 = *(const bf16x8*)(ph + 32);
            al0 = *(const bf16x8*)(pl);
            al1 = *(const bf16x8*)(pl + 32);
        } else {
            #pragma unroll
            for (int e = 0; e < 8; ++e) { ah0[e] = 0; ah1[e] = 0; al0[e] = 0; al1[e] = 0; }
        }
        f32x4 acc[4] = {{0.f,0.f,0.f,0.f},{0.f,0.f,0.f,0.f},{0.f,0.f,0.f,0.f},{0.f,0.f,0.f,0.f}};
        #pragma unroll
        for (int t4 = 0; t4 < 4; ++t4) {
            #pragma unroll
            for (int s = 0; s < 2; ++s) {
                bf16x8 bh = *(const bf16x8*)(wp + (size_t)((t4 * 2 + s) * 512) + lane * 8);
                bf16x8 a_h = s ? ah1 : ah0;
                bf16x8 a_l = s ? al1 : al0;
                acc[t4] = __builtin_amdgcn_mfma_f32_16x16x32_bf16(a_l, bh, acc[t4], 0, 0, 0);
                acc[t4] = __builtin_amdgcn_mfma_f32_16x16x32_bf16(a_h, bh, acc[t4], 0, 0, 0);
            }
        }
        #pragma unroll
        for (int t4 = 0; t4 < 4; ++t4) {
            float b = bb[t4 * 16 + c];
            #pragma unroll
            for (int r = 0; r < 4; ++r) {
                float y = fmaxf(acc[t4][r] + b, 0.f);
                __hip_bfloat16 hb = __float2bfloat16(y);
                __hip_bfloat16 lb = __float2bfloat16(y - __bfloat162float(hb));
                int rw = mt * 16 + q * 4 + r;
                mys[rw * 136 + t4 * 16 + c]       = *(ushort_t*)&hb;
                mys[rw * 136 + 64 + t4 * 16 + c]  = *(ushort_t*)&lb;
            }
        }
    }
    __syncthreads();

    // ---- GEMM2 (A = planar y from LDS: direct bf16x8 loads, no unpack) ----
    float ssum[4] = {0.f, 0.f, 0.f, 0.f};
    float ssq[4] = {0.f, 0.f, 0.f, 0.f};
    #pragma unroll
    for (int mt = 0; mt < 2; ++mt) {
        int nl = mt * 16 + c;
        bf16x8 yah[2], yal[2];
        #pragma unroll
        for (int s = 0; s < 2; ++s) {
            yah[s] = *(const bf16x8*)(mys + nl * 136 + s * 32 + q * 8);
            yal[s] = *(const bf16x8*)(mys + nl * 136 + 64 + s * 32 + q * 8);
        }
        f32x4 acc[4] = {{0.f,0.f,0.f,0.f},{0.f,0.f,0.f,0.f},{0.f,0.f,0.f,0.f},{0.f,0.f,0.f,0.f}};
        #pragma unroll
        for (int t4 = 0; t4 < 4; ++t4) {
            #pragma unroll
            for (int s = 0; s < 2; ++s) {
                bf16x8 bh = *(const bf16x8*)(wp + (size_t)((16 + t4 * 2 + s) * 512) + lane * 8);
                acc[t4] = __builtin_amdgcn_mfma_f32_16x16x32_bf16(yal[s], bh, acc[t4], 0, 0, 0);
                acc[t4] = __builtin_amdgcn_mfma_f32_16x16x32_bf16(yah[s], bh, acc[t4], 0, 0, 0);
            }
        }
        #pragma unroll
        for (int t4 = 0; t4 < 4; ++t4) {
            float b = bb[64 + t4 * 16 + c];
            #pragma unroll
            for (int r = 0; r < 4; ++r) {
                int node = nb + mt * 16 + q * 4 + r;
                float h = fmaxf(acc[t4][r] + b, 0.f);
                float hv = (node < n) ? h : 0.f;
                ssum[t4] += hv;
                ssq[t4] += hv * hv;
                my[(mt * 16 + q * 4 + r) * YSTRIDE + t4 * 16 + c] = __float_as_uint(h);
            }
        }
    }
    __syncthreads();

    // stats butterfly across the 4 quadrants (rows); lanes 0..15 store
    #pragma unroll
    for (int t4 = 0; t4 < 4; ++t4) {
        ssum[t4] += __shfl_xor(ssum[t4], 16, 64);
        ssum[t4] += __shfl_xor(ssum[t4], 32, 64);
        ssq[t4]  += __shfl_xor(ssq[t4], 16, 64);
        ssq[t4]  += __shfl_xor(ssq[t4], 32, 64);
    }
    if (lane < 16) {
        #pragma unroll
        for (int t4 = 0; t4 < 4; ++t4) {
            partials[(size_t)(t4 * 16 + lane) * NWAVE + wid] = ssum[t4];
            partials[(size_t)(64 + t4 * 16 + lane) * NWAVE + wid] = ssq[t4];
        }
    }

    // store phase: coalesced (zh, zl) from LDS h
    #pragma unroll
    for (int cc = 0; cc < 8; ++cc) {
        int li = lane + 64 * cc;
        int nl = li >> 4, fg = li & 15;
        int node = nb + nl;
        if (node < n) {
            uint4 u = *(const uint4*)(my + nl * YSTRIDE + fg * 4);
            float f0 = __uint_as_float(u.x);
            float f1 = __uint_as_float(u.y);
            float f2 = __uint_as_float(u.z);
            float f3 = __uint_as_float(u.w);
            __hip_bfloat16 h0 = __float2bfloat16(f0);
            __hip_bfloat16 h1 = __float2bfloat16(f1);
            __hip_bfloat16 h2 = __float2bfloat16(f2);
            __hip_bfloat16 h3 = __float2bfloat16(f3);
            __hip_bfloat16 l0 = __float2bfloat16(f0 - __bfloat162float(h0));
            __hip_bfloat16 l1 = __float2bfloat16(f1 - __bfloat162float(h1));
            __hip_bfloat16 l2 = __float2bfloat16(f2 - __bfloat162float(h2));
            __hip_bfloat16 l3 = __float2bfloat16(f3 - __bfloat162float(h3));
            uint2 ph, pl;
            ph.x = (uint_t)*(ushort_t*)&h0 | ((uint_t)*(ushort_t*)&h1 << 16);
            ph.y = (uint_t)*(ushort_t*)&h2 | ((uint_t)*(ushort_t*)&h3 << 16);
            pl.x = (uint_t)*(ushort_t*)&l0 | ((uint_t)*(ushort_t*)&l1 << 16);
            pl.y = (uint_t)*(ushort_t*)&l2 | ((uint_t)*(ushort_t*)&l3 << 16);
            *(uint2*)(zh_out + (size_t)node * 64 + fg * 4) = ph;
            *(uint2*)(zl_out + (size_t)node * 64 + fg * 4) = pl;
        }
    }
}

// reduce per-wave partials -> BN affine (A,C) for this layer's ac slot.
__global__ __launch_bounds__(256) void redstats_kernel(
    const float* __restrict__ partials, const float* __restrict__ gammaf,
    const float* __restrict__ betaf, float* __restrict__ ac_out)
{
    __shared__ float s1[256], s2[256];
    int f = blockIdx.x;
    int t = threadIdx.x;
    const float* ph = partials + (size_t)f * NWAVE;
    const float* pq = partials + (size_t)(64 + f) * NWAVE;
    float a = 0.f, b = 0.f;
    for (int i = t; i < NWAVE; i += 256) { a += ph[i]; b += pq[i]; }
    s1[t] = a; s2[t] = b;
    __syncthreads();
    for (int off = 128; off > 0; off >>= 1) {
        if (t < off) { s1[t] += s1[t + off]; s2[t] += s2[t + off]; }
        __syncthreads();
    }
    if (t == 0) {
        const float invN = 1.0f / (float)NN;
        float mu = s1[0] * invN;
        float var = s2[0] * invN - mu * mu;
        if (var < 0.f) var = 0.f;
        float A = gammaf[f] * rsqrtf(var + 1e-5f);
        float C = betaf[f] - mu * A;
        ac_out[f] = A;
        ac_out[64 + f] = C;
    }
}

// final pool (layer 3 only): p = node_pool + (A*z+C); out node section = p;
// gpool = run-length segsum of p (== segsum(node_pool_final), linearity).
__global__ __launch_bounds__(256) void pool_kernel(
    const ushort_t* __restrict__ zh, const ushort_t* __restrict__ zl,
    const float* __restrict__ node_pool, const int* __restrict__ b32,
    const float* __restrict__ ac, float* __restrict__ gpool,
    const int* __restrict__ flags, void* __restrict__ out, int N)
{
    int wave = (blockIdx.x * 256 + threadIdx.x) >> 6;
    int f = threadIdx.x & 63;
    int n0 = wave * 16;
    if (n0 >= N) return;
    int n1 = min(n0 + 16, N);
    float A = ac[f], C = ac[64 + f];
    int fp32 = flags[0];
    float racc = 0.f;
    int cur = b32[n0];
    int n = n0;
    for (; n + 4 <= n1; n += 4) {
        int4 gv = *(const int4*)(b32 + n);
        size_t idx = (size_t)n * 64 + f;
        float z0 = __uint_as_float((uint_t)zh[idx] << 16)       + __uint_as_float((uint_t)zl[idx] << 16);
        float z1 = __uint_as_float((uint_t)zh[idx + 64] << 16)  + __uint_as_float((uint_t)zl[idx + 64] << 16);
        float z2 = __uint_as_float((uint_t)zh[idx + 128] << 16) + __uint_as_float((uint_t)zl[idx + 128] << 16);
        float z3 = __uint_as_float((uint_t)zh[idx + 192] << 16) + __uint_as_float((uint_t)zl[idx + 192] << 16);
        float p0 = node_pool[idx]       + fmaf(z0, A, C);
        float p1 = node_pool[idx + 64]  + fmaf(z1, A, C);
        float p2 = node_pool[idx + 128] + fmaf(z2, A, C);
        float p3 = node_pool[idx + 192] + fmaf(z3, A, C);
        if (fp32) {
            ((float*)out)[idx]       = p0;
            ((float*)out)[idx + 64]  = p1;
            ((float*)out)[idx + 128] = p2;
            ((float*)out)[idx + 192] = p3;
        } else {
            __hip_bfloat16 b0 = __float2bfloat16(p0);
            __hip_bfloat16 b1 = __float2bfloat16(p1);
            __hip_bfloat16 b2 = __float2bfloat16(p2);
            __hip_bfloat16 b3 = __float2bfloat16(p3);
            ((__hip_bfloat16*)out)[idx]       = b0;
            ((__hip_bfloat16*)out)[idx + 64]  = b1;
            ((__hip_bfloat16*)out)[idx + 128] = b2;
            ((__hip_bfloat16*)out)[idx + 192] = b3;
        }
        int gs0 = gv.x, gs1 = gv.y, gs2 = gv.z, gs3 = gv.w;
        if (gs0 != cur) { atomicAdd(&gpool[(size_t)cur * 64 + f], racc); racc = 0.f; cur = gs0; }
        racc += p0;
        if (gs1 != cur) { atomicAdd(&gpool[(size_t)cur * 64 + f], racc); racc = 0.f; cur = gs1; }
        racc += p1;
        if (gs2 != cur) { atomicAdd(&gpool[(size_t)cur * 64 + f], racc); racc = 0.f; cur = gs2; }
        racc += p2;
        if (gs3 != cur) { atomicAdd(&gpool[(size_t)cur * 64 + f], racc); racc = 0.f; cur = gs3; }
        racc += p3;
    }
    for (; n < n1; ++n) {  // tail (unused when 16 | N; kept for safety)
        int g = b32[n];
        if (g != cur) { atomicAdd(&gpool[(size_t)cur * 64 + f], racc); racc = 0.f; cur = g; }
        size_t idx = (size_t)n * 64 + f;
        float zv = __uint_as_float((uint_t)zh[idx] << 16) + __uint_as_float((uint_t)zl[idx] << 16);
        float p = node_pool[idx] + fmaf(zv, A, C);
        if (fp32) ((float*)out)[idx] = p;
        else ((__hip_bfloat16*)out)[idx] = __float2bfloat16(p);
        racc += p;
    }
    atomicAdd(&gpool[(size_t)cur * 64 + f], racc);
}

// finalize: gpool tail only (node section written by pool)
__global__ __launch_bounds__(256) void finalize_kernel(
    const float* __restrict__ gpool, const float* __restrict__ invg,
    const int* __restrict__ flags, void* __restrict__ out, int N)
{
    int i = blockIdx.x * 256 + threadIdx.x;
    if (i >= GG * 64) return;
    float v = gpool[i] * invg[i >> 6];
    int nd = N * 64;
    if (flags[0]) ((float*)out)[nd + i] = v;
    else ((__hip_bfloat16*)out)[nd + i] = __float2bfloat16(v);
}

extern "C" void kernel_launch(void* const* d_in, const int* in_sizes, int n_in,
                              void* d_out, int out_size, void* d_ws, size_t ws_size,
                              hipStream_t stream)
{
    constexpr int N = NN, E = EE, G = GG;
    constexpr int ND = N * 64;

    const void* x     = d_in[0];
    const void* W1    = d_in[1];
    const void* b1    = d_in[2];
    const void* W2    = d_in[3];
    const void* b2    = d_in[4];
    const void* gamma = d_in[5];
    const void* beta  = d_in[6];
    const int* ei     = (const int*)d_in[7];
    const int* batw   = (const int*)d_in[8];

    char* p = (char*)d_ws;
    auto alloc = [&](size_t bytes) -> char* {
        char* r = p;
        p += (bytes + 255) & ~(size_t)255;
        return r;
    };
    ushort_t* zhA      = (ushort_t*)alloc((size_t)ND * 2);
    ushort_t* zlA      = (ushort_t*)alloc((size_t)ND * 2);
    ushort_t* zhB      = (ushort_t*)alloc((size_t)ND * 2);
    ushort_t* zlB      = (ushort_t*)alloc((size_t)ND * 2);
    float*    node_pool = (float*)alloc((size_t)ND * 4);
    int*      esrc      = (int*)alloc((size_t)E * 4);
    int*      indptr    = (int*)alloc((size_t)(N + 1) * 4);
    int*      deg       = (int*)alloc((size_t)N * 4);
    int*      part      = (int*)alloc((size_t)N * 4);
    float*    invdeg    = (float*)alloc((size_t)N * 4);
    int*      b32       = (int*)alloc((size_t)N * 4);
    int*      bsum      = (int*)alloc(128 * 4);
    int*      gstart    = (int*)alloc((size_t)(G + 1) * 4);
    float*    invg      = (float*)alloc(G * 4);
    float*    gpool     = (float*)alloc((size_t)G * 64 * 4);
    float*    ac5       = (float*)alloc(5 * 128 * 4);  // slot0 identity, slots1..4 BN_l
    float*    partials  = (float*)alloc((size_t)128 * NWAVE * 4);  // 1.6 MB
    ushort_t* wp        = (ushort_t*)alloc((size_t)4 * 16384 * 2); // packed weights
    float*    bb        = (float*)alloc(4 * 256 * 4);  // b1,b2,gamma,beta per layer
    int*      flags     = (int*)alloc(16 * 4);
    int*      histo     = (int*)alloc((size_t)NBK * NHB * 4);
    int*      tot       = (int*)alloc((size_t)NBK * 4);
    int*      bktoff    = (int*)alloc((size_t)(NBK + 1) * 4);
    // pairs aliases node_pool: dead until agg_1's folded pool; E*8 == ND*4 bytes
    int2*     pairs     = (int2*)node_pool;

    hipMemsetAsync(gpool, 0, (size_t)G * 64 * 4, stream);

    detect_kernel<<<1, 256, 0, stream>>>(
        (const uint_t*)x, (const uint_t*)ei, (const uint_t*)batw, flags);
    cvt_w_kernel<<<260, 256, 0, stream>>>(W1, b1, W2, b2, gamma, beta, flags, wp, bb);
    cvt_x_kernel<<<(ND + 255) / 256, 256, 0, stream>>>(x, flags, zhA, zlA, ND);
    cvt_batch_kernel<<<(N + 255) / 256, 256, 0, stream>>>(batw, flags, b32, gstart, N);
    count_hist_kernel<<<NHB, 256, 0, stream>>>(ei, flags, histo, E);
    blockscan_kernel<<<NBK, NHB, 0, stream>>>(histo, tot);
    bscan_kernel<<<1, 512, 0, stream>>>(tot, bktoff);
    pair_scatter_kernel<<<NHB, 256, 0, stream>>>(ei, flags, histo, bktoff, pairs, E);
    bucket_deg_kernel<<<NBK, 256, 0, stream>>>(pairs, bktoff, deg, N);
    int nb = (N + 1023) / 1024;  // 98
    scan1_kernel<<<nb, 256, 0, stream>>>(deg, part, bsum, N);
    scan2_kernel<<<1, 128, 0, stream>>>(bsum, nb);
    scan3_kernel<<<(N + 255) / 256, 256, 0, stream>>>(part, bsum, deg, indptr, invdeg, N);
    invg_kernel<<<1, 512, 0, stream>>>(gstart, invg, ac5, G);
    csr_fill_kernel<<<NBK, 256, 0, stream>>>(pairs, bktoff, indptr, esrc, N);

    for (int l = 0; l < 4; ++l) {
        agg_kernel<<<(N + 15) / 16, 256, 0, stream>>>(
            zhA, zlA, indptr, esrc, invdeg, ac5 + l * 128,
            zhB, zlB, node_pool, (l >= 1) ? 1 : 0, (l == 1) ? 1 : 0, N);
        mlp_kernel<<<MLPBLOCKS, 256, 0, stream>>>(
            zhB, zlB, wp + (size_t)l * 16384, bb + l * 256,
            zhA, zlA, partials, N);
        redstats_kernel<<<64, 256, 0, stream>>>(
            partials, bb + l * 256 + 128, bb + l * 256 + 192,
            ac5 + (l + 1) * 128);
    }
    // final pool: p = node_pool + h_3; out node section = p; gpool = segsum(p)
    pool_kernel<<<(N + 63) / 64, 256, 0, stream>>>(
        zhA, zlA, node_pool, b32, ac5 + 4 * 128, gpool, flags, d_out, N);
    finalize_kernel<<<128, 256, 0, stream>>>(gpool, invg, flags, d_out, N);
}